// Round 17
// baseline (188.956 us; speedup 1.0000x reference)
//
#include <hip/hip_runtime.h>

// B=2, T=2048, C=1024, H=16, D=64. Inputs fp32, OUTPUT fp32.
// Round 29 (post-mortem R28: flash 52.0 (conflicts 6.5M->4.3M, residual is
// intrinsic multi-round b128 cost; flash at structural latency floor).
// Accounting: total 184 - flash 52 - (prep 9 + proj 14 + gaps 10) leaves
// qkv at ~60-75us — it is the weak structure (BK=32: 16 MFMA per stage+2
// barriers x32 periods)):
//  - qkv_rope_k: m97 structure — BK=64 SINGLE-buffered As/Bs[128][64]
//    (32KB, unions under 34.8KB epilogue Ct), 16 K-periods of
//    {8 gload16, vmcnt(0), barrier, 32 MFMA, barrier}. 8-slot XOR swizzle
//    (slot^=row&7 source-side; read ((ks>>3)+quad)^(lr&7)) — proj-verified.
//  - prep_k / flash_k / proj_k unchanged from R28.
// MFMA 16x16x32_bf16 layouts (HW-verified): A: m=lane&15,k=quad*8+j;
// B: k=quad*8+j,n=lane&15; C/D: col=lane&15,row=quad*4+reg.
// MFMA 16x16x16_bf16 (HW-verified R17): A: m=lane&15,k=quad*4+j;
// B: k=quad*4+j,n=lane&15; C/D: col=lane&15,row=quad*4+reg.

typedef unsigned short u16;
typedef u16 u16x4 __attribute__((ext_vector_type(4)));
typedef u16 u16x8 __attribute__((ext_vector_type(8)));
typedef short s16x4 __attribute__((ext_vector_type(4)));
typedef short s16x8 __attribute__((ext_vector_type(8)));
typedef float f32x4 __attribute__((ext_vector_type(4)));

#define T_SEQ 2048
#define C_EMB 1024
#define NH 16
#define HD 64

#define MFMA16(a, b, c) __builtin_amdgcn_mfma_f32_16x16x32_bf16(a, b, c, 0, 0, 0)

__device__ __forceinline__ f32x4 MFMA16K16(s16x4 a, s16x4 b, f32x4 c) {
#if __has_builtin(__builtin_amdgcn_mfma_f32_16x16x16bf16_1k)
    return __builtin_amdgcn_mfma_f32_16x16x16bf16_1k(a, b, c, 0, 0, 0);
#else
    asm("v_mfma_f32_16x16x16_bf16 %0, %1, %2, %0" : "+v"(c) : "v"(a), "v"(b));
    return c;
#endif
}

__device__ __forceinline__ u16 f2bf(float f) {
    union { float f; unsigned int i; } x; x.f = f;
    unsigned int r = x.i + 0x7fffu + ((x.i >> 16) & 1u);
    return (u16)(r >> 16);
}
__device__ __forceinline__ u16x4 pack4(f32x4 v) {
    u16x4 o;
#pragma unroll
    for (int j = 0; j < 4; ++j) o[j] = f2bf(v[j]);
    return o;
}
// hot-loop pack: HW packed convert (RNE), 2 instr per 4 values -> s16x4 frag
__device__ __forceinline__ s16x4 pack4cvt_s(f32x4 v) {
    union { s16x4 h; unsigned int w[2]; } u;
    asm("v_cvt_pk_bf16_f32 %0, %1, %2" : "=v"(u.w[0]) : "v"(v[0]), "v"(v[1]));
    asm("v_cvt_pk_bf16_f32 %0, %1, %2" : "=v"(u.w[1]) : "v"(v[2]), "v"(v[3]));
    return u.h;
}
// async global->LDS, 16B per lane (dest must be wave-uniform base + lane*16)
__device__ __forceinline__ void gload16(const void* g, void* l) {
    __builtin_amdgcn_global_load_lds(
        (const __attribute__((address_space(1))) unsigned int*)g,
        (__attribute__((address_space(3))) unsigned int*)l, 16, 0, 0);
}

// ---------------- k0: merged prep (3x fp32->bf16 conv + rope tables) -------
// grid 4352: [0,2048) conv x; [2048,3584) conv Wa; [3584,4096) conv Wp;
// [4096,4352) rope tables. All sections exact-sized (no bounds checks).
__global__ __launch_bounds__(256) void prep_k(const float* __restrict__ x, const float* __restrict__ Wa,
                                              const float* __restrict__ Wp,
                                              u16* __restrict__ xb, u16* __restrict__ Wab,
                                              u16* __restrict__ Wpb, float2* __restrict__ tab) {
    int bid = blockIdx.x, tid = threadIdx.x;
    if (bid < 4096) {
        const float* src;
        u16* dst;
        int i;
        if (bid < 2048)      { src = x;  dst = xb;  i = bid * 256 + tid; }
        else if (bid < 3584) { src = Wa; dst = Wab; i = (bid - 2048) * 256 + tid; }
        else                 { src = Wp; dst = Wpb; i = (bid - 3584) * 256 + tid; }
        f32x4 a = ((const f32x4*)src)[i * 2];
        f32x4 b = ((const f32x4*)src)[i * 2 + 1];
        u16x8 o;
#pragma unroll
        for (int j = 0; j < 4; ++j) o[j] = f2bf(a[j]);
#pragma unroll
        for (int j = 0; j < 4; ++j) o[4 + j] = f2bf(b[j]);
        ((u16x8*)dst)[i] = o;
    } else {
        int idx = (bid - 4096) * 256 + tid;   // 65536 = T*32
        int t = idx >> 5, j = idx & 31;
        float inv = __builtin_exp2f(-0.41524101186092f * (float)j);  // 10000^(-j/32)
        float s_, c_;
        sincosf((float)t * inv, &s_, &c_);
        tab[idx] = make_float2(c_, s_);
    }
}

// ---------------- k1: QKV GEMM + RoPE (m97 structure: BK=64, single-buf) ---
// grid (24, 32): n0 = bx*128 (0..3071), m0 = by*128 (0..4095)
// 16 K-periods: {8 gload16/thread, vmcnt(0), barrier, 32 MFMA, barrier}.
// As/Bs [128][64] linear (content XOR-swizzled, 8 slots); 32KB, unions
// under the 34.8KB epilogue Ct.
__global__ __launch_bounds__(256) void qkv_rope_k(const u16* __restrict__ xb, const u16* __restrict__ Wab,
                                                  const float* __restrict__ bias,
                                                  const float2* __restrict__ tab,
                                                  u16* __restrict__ qb, u16* __restrict__ kb,
                                                  u16* __restrict__ vt) {
    __shared__ u16 smem[17408];               // As[8192] | Bs[8192]; epilogue Ct[17408]
    u16* As = smem;                           // [128][64] linear (content swizzled)
    u16* Bs = smem + 8192;
    int tid = threadIdx.x;
    int n0 = blockIdx.x * 128, m0 = blockIdx.y * 128;
    int w = tid >> 6, lane = tid & 63, lr = lane & 15, quad = lane >> 4;
    int wr = w >> 1, wc = w & 1;
    f32x4 acc[4][4] = {};
    int srow = tid >> 3;                                  // staging row 0..31 (+32k per it)
    int swc8 = (((tid & 7) ^ (srow & 7)) << 3);           // pre-swizzled src col (u16)
    int lrx = lr & 7;                                     // fragment-read XOR key

    for (int kt = 0; kt < C_EMB; kt += 64) {
#pragma unroll
        for (int it = 0; it < 4; ++it) {
            int row = it * 32 + srow;          // row&7 == srow&7 (32|8)
            int off = it * 2048 + tid * 8;     // linear u16 LDS offset
            gload16(xb  + (size_t)(m0 + row) * C_EMB + kt + swc8, &As[off]);
            gload16(Wab + (size_t)(n0 + row) * C_EMB + kt + swc8, &Bs[off]);
        }
        asm volatile("s_waitcnt vmcnt(0)" ::: "memory");
        __builtin_amdgcn_s_barrier();
        asm volatile("" ::: "memory");
#pragma unroll
        for (int ks = 0; ks < 64; ks += 32) {
            int rc8 = ((((ks >> 3) + quad) ^ lrx) << 3);   // swizzled read col (u16)
            s16x8 af[4], bf[4];
#pragma unroll
            for (int i = 0; i < 4; ++i)
                af[i] = *(const s16x8*)&As[(wr * 64 + i * 16 + lr) * 64 + rc8];
#pragma unroll
            for (int j = 0; j < 4; ++j)
                bf[j] = *(const s16x8*)&Bs[(wc * 64 + j * 16 + lr) * 64 + rc8];
#pragma unroll
            for (int i = 0; i < 4; ++i)
#pragma unroll
                for (int j = 0; j < 4; ++j) acc[i][j] = MFMA16(af[i], bf[j], acc[i][j]);
        }
        asm volatile("" ::: "memory");
        __builtin_amdgcn_s_barrier();
    }

    int sec = n0 >> 10;                       // 0=q 1=k 2=v (blocks never straddle)
    float bv[4];
#pragma unroll
    for (int j = 0; j < 4; ++j) bv[j] = bias[n0 + wc * 64 + j * 16 + lr];

    int h0 = (n0 & 1023) >> 6;
    int b = m0 >> 11, tbase = m0 & 2047;
    if (sec == 2) {
        // C tile (+bias) -> LDS [d][m] (136-padded) -> coalesced 16B
        // transposed stores to vt[((b*16+h)*64+d)*2048 + t].
        u16* Ct = smem;                        // 128 x 136 u16 = 34816 B
#pragma unroll
        for (int i = 0; i < 4; ++i)
#pragma unroll
            for (int j = 0; j < 4; ++j) {
                f32x4 vv;
#pragma unroll
                for (int r = 0; r < 4; ++r) vv[r] = acc[i][j][r] + bv[j];
                int d = wc * 64 + j * 16 + lr;
                int m4 = wr * 64 + i * 16 + quad * 4;
                *(u16x4*)&Ct[d * 136 + m4] = pack4(vv);
            }
        __syncthreads();
        size_t hb = (size_t)(b * NH);
#pragma unroll
        for (int p = 0; p < 8; ++p) {
            int idx = p * 256 + tid;
            int d = idx >> 4, mc = (idx & 15) << 3;
            s16x8 vdat = *(const s16x8*)&Ct[d * 136 + mc];
            int h = h0 + (d >> 6), dd = d & 63;
            *(s16x8*)(vt + ((hb + h) * HD + dd) * T_SEQ + tbase + mc) = vdat;
        }
    } else {
        // q/k: RoPE in-register, stage [m][n] in LDS, coalesced b128 stores.
        u16* dst = (sec == 0) ? qb : kb;
        // fold 1/sqrt(D) AND log2(e) into q so flash softmax is native base-2:
        float qs = (sec == 0) ? 0.18033688011112043f : 1.0f;
        u16* Ct = smem;                        // 128 x 136 u16
        __syncthreads();                       // all frag reads done before overwrite
#pragma unroll
        for (int i = 0; i < 4; ++i)
#pragma unroll
            for (int r = 0; r < 4; ++r) {
                int mrow = wr * 64 + i * 16 + quad * 4 + r;
                int t = (m0 + mrow) & 2047;
#pragma unroll
                for (int j = 0; j < 2; ++j) {
                    int d1 = j * 16 + lr;                 // 0..31; partner +32 in tile j+2
                    float2 cs = tab[t * 32 + d1];
                    float v1 = acc[i][j][r] + bv[j];
                    float v2 = acc[i][j + 2][r] + bv[j + 2];
                    int n1 = wc * 64 + j * 16 + lr;
                    Ct[mrow * 136 + n1]      = f2bf((v1 * cs.x - v2 * cs.y) * qs);
                    Ct[mrow * 136 + n1 + 32] = f2bf((v2 * cs.x + v1 * cs.y) * qs);
                }
            }
        __syncthreads();
#pragma unroll
        for (int p = 0; p < 8; ++p) {
            int idx = p * 256 + tid;              // 128 rows x 16 chunks of 8 u16
            int mrow = idx >> 4, c = idx & 15;
            s16x8 vdat = *(const s16x8*)&Ct[mrow * 136 + c * 8];
            int h = h0 + (c >> 3), dd = (c & 7) << 3;
            *(s16x8*)(dst + ((size_t)(b * NH + h) * T_SEQ + tbase + mrow) * HD + dd) = vdat;
        }
    }
}

// ---------------- k2: flash attention (64-row Q tile, XOR-swizzled LDS) ----
// grid (32, 32), 256 threads / 4 waves / 1 strip each. qt = q-tile of 64
// rows; wave w owns rows [qt*64+16w, +16). 1024 blocks = whole grid
// co-resident at 4 blocks/CU (LDS 32KB). Mask only on kt==qt.
// K/V LDS: [64][64] linear, 8-slot XOR swizzle LDS[row][s]=G[row][s^(row&7)]
// (reg-staged writes swizzle the LDS addr). ak slot=(ks*4+quad)^(lr&7);
// av slot=(2tc+(quad>>1))^(lr&7), +4 u16 if quad odd. All bank-uniform.
// S^T: elem (k'=k0+tc*16+quad*4+r, q=rbase+lr). PV: 16x16x16, P in regs.
// Double-buffered K/V, one barrier per k-tile. T5 setprio around MFMAs.
__global__ __launch_bounds__(256, 4) void flash_k(const u16* __restrict__ qb, const u16* __restrict__ kb,
                                                  const u16* __restrict__ vt, u16* __restrict__ yab) {
    __shared__ u16 Ks[2][64 * 64];
    __shared__ u16 Vs[2][64 * 64];
    int tid = threadIdx.x;
    int bx = blockIdx.x, by = blockIdx.y;
    int qt = (by < 16) ? (31 - bx) : bx;      // complementary pairing for balance
    int bh = by;
    int w = tid >> 6, lane = tid & 63, lr = lane & 15, quad = lane >> 4;
    int q0 = qt * 64;
    const u16* qh = qb + (size_t)bh * T_SEQ * HD;
    const u16* kh = kb + (size_t)bh * T_SEQ * HD;
    const u16* vh = vt + (size_t)bh * HD * T_SEQ;

    int rbase = q0 + w * 16;                  // this wave's strip

    s16x8 aq[2];                              // B-frag of Q (n=q-row=lr, k=d)
#pragma unroll
    for (int ks = 0; ks < 2; ++ks)
        aq[ks] = *(const s16x8*)(qh + (size_t)(rbase + lr) * HD + ks * 32 + quad * 8);

    int srow = tid >> 3, sc8 = (tid & 7) << 3;       // staging: rows srow, srow+32
    int swsl = (((tid & 7) ^ (srow & 7)) << 3);      // swizzled LDS write col (u16)
    int lrx8 = (lr & 7) << 3;                        // fragment-read XOR key (u16 units)

    float m_i = -1e30f;
    f32x4 l4 = {0.f, 0.f, 0.f, 0.f};          // per-lane l partials
    f32x4 oacc[4] = {};                       // O^T: elem (d=dn*16+quad*4+r, q=lr)

    int ktmax = qt;
    {   // prologue: stage tile 0 into buffer 0 (2 K-rows + 2 V-rows / thread)
        s16x8 ka = *(const s16x8*)(kh + (size_t)srow * HD + sc8);
        s16x8 kb2 = *(const s16x8*)(kh + (size_t)(srow + 32) * HD + sc8);
        s16x8 va = *(const s16x8*)(vh + (size_t)srow * T_SEQ + sc8);
        s16x8 vb = *(const s16x8*)(vh + (size_t)(srow + 32) * T_SEQ + sc8);
        *(s16x8*)&Ks[0][srow * 64 + swsl] = ka;
        *(s16x8*)&Ks[0][(srow + 32) * 64 + swsl] = kb2;
        *(s16x8*)&Vs[0][srow * 64 + swsl] = va;
        *(s16x8*)&Vs[0][(srow + 32) * 64 + swsl] = vb;
    }
    __syncthreads();

    for (int kt = 0; kt <= ktmax; ++kt) {
        int cur = kt & 1;
        int k0 = kt * 64;
        bool pf = kt < ktmax;
        s16x8 kr0, kr1, vr0, vr1;             // next-tile prefetch registers
        if (pf) {
            int kn = k0 + 64;
            kr0 = *(const s16x8*)(kh + (size_t)(kn + srow) * HD + sc8);
            kr1 = *(const s16x8*)(kh + (size_t)(kn + srow + 32) * HD + sc8);
            vr0 = *(const s16x8*)(vh + (size_t)srow * T_SEQ + kn + sc8);
            vr1 = *(const s16x8*)(vh + (size_t)(srow + 32) * T_SEQ + kn + sc8);
        }
        const u16* Kc = Ks[cur];
        const u16* Vc = Vs[cur];

        // fragments (all strips active every tile in the 64-row form)
        s16x8 ak[2][4];                       // K frag (m=k-row=lr, k=d)
#pragma unroll
        for (int ks = 0; ks < 2; ++ks)
#pragma unroll
            for (int tc = 0; tc < 4; ++tc)
                ak[ks][tc] = *(const s16x8*)&Kc[(tc * 16 + lr) * 64 + (((ks * 4 + quad) << 3) ^ lrx8)];
        s16x4 av[4][4];                       // V^T frag (m=d=dn*16+lr, k=tc*16+quad*4+j)
#pragma unroll
        for (int dn = 0; dn < 4; ++dn) {
            const u16* vrow = &Vc[(dn * 16 + lr) * 64 + ((quad & 1) << 2)];
#pragma unroll
            for (int tc = 0; tc < 4; ++tc)
                av[dn][tc] = *(const s16x4*)(vrow + ((((tc << 1) + (quad >> 1)) << 3) ^ lrx8));
        }
        f32x4 sacc[4] = {};
        __builtin_amdgcn_s_setprio(1);        // T5: favor MFMA wave
#pragma unroll
        for (int ks = 0; ks < 2; ++ks)
#pragma unroll
            for (int tc = 0; tc < 4; ++tc) sacc[tc] = MFMA16(ak[ks][tc], aq[ks], sacc[tc]);
        __builtin_amdgcn_s_setprio(0);
        if (kt == ktmax) {                    // diagonal tile: causal mask
#pragma unroll
            for (int tc = 0; tc < 4; ++tc)
#pragma unroll
                for (int r = 0; r < 4; ++r)
                    if (k0 + tc * 16 + quad * 4 + r > rbase + lr) sacc[tc][r] = -1e30f;
        }
        // per-lane local max; __all == row-max guard
        f32x4 mv = sacc[0];
#pragma unroll
        for (int tc = 1; tc < 4; ++tc)
#pragma unroll
            for (int r = 0; r < 4; ++r) mv[r] = fmaxf(mv[r], sacc[tc][r]);
        float loc = fmaxf(fmaxf(mv[0], mv[1]), fmaxf(mv[2], mv[3]));
        bool need = !__all(loc <= m_i + 8.0f);   // defer-max (T13, THR=8)
        float alpha = 1.0f;
        if (need) {                            // rare: full cross-lane max
            float mx = fmaxf(loc, __shfl_xor(loc, 16, 64));
            mx = fmaxf(mx, __shfl_xor(mx, 32, 64));
            float mn = fmaxf(m_i, mx);
            alpha = __builtin_exp2f(m_i - mn);
            m_i = mn;
#pragma unroll
            for (int r = 0; r < 4; ++r) l4[r] *= alpha;
        }
        float mnow = m_i;
#pragma unroll
        for (int tc = 0; tc < 4; ++tc)
#pragma unroll
            for (int r = 0; r < 4; ++r) {
                float p = __builtin_exp2f(sacc[tc][r] - mnow);
                sacc[tc][r] = p;
                l4[r] += p;                    // per-lane partial; folded at end
            }
        // P in registers: pack4cvt(sacc[tc]) IS the 16x16x16 B-frag
        s16x4 pa[4];
#pragma unroll
        for (int tc = 0; tc < 4; ++tc) pa[tc] = pack4cvt_s(sacc[tc]);
        if (need) {
#pragma unroll
            for (int dn = 0; dn < 4; ++dn)
#pragma unroll
                for (int r = 0; r < 4; ++r) oacc[dn][r] *= alpha;
        }
        __builtin_amdgcn_s_setprio(1);        // T5: favor MFMA wave
#pragma unroll
        for (int dn = 0; dn < 4; ++dn)
#pragma unroll
            for (int tc = 0; tc < 4; ++tc)
                oacc[dn] = MFMA16K16(av[dn][tc], pa[tc], oacc[dn]);
        __builtin_amdgcn_s_setprio(0);

        if (pf) {                              // write prefetched tile to other buffer
            int nx = cur ^ 1;
            *(s16x8*)&Ks[nx][srow * 64 + swsl] = kr0;
            *(s16x8*)&Ks[nx][(srow + 32) * 64 + swsl] = kr1;
            *(s16x8*)&Vs[nx][srow * 64 + swsl] = vr0;
            *(s16x8*)&Vs[nx][(srow + 32) * 64 + swsl] = vr1;
        }
        __syncthreads();                       // single barrier per k-tile
    }
    // fold l partials: 4 per-lane + the 4 lanes of each row (xor 16, 32)
    float rs = (l4[0] + l4[1]) + (l4[2] + l4[3]);
    rs += __shfl_xor(rs, 16, 64);
    rs += __shfl_xor(rs, 32, 64);
    int b = bh >> 4, hh = bh & 15;
    {
        float inv = 1.f / rs;
        int t = rbase + lr;
        size_t base = ((size_t)b * T_SEQ + t) * C_EMB + hh * HD;
#pragma unroll
        for (int dn = 0; dn < 4; ++dn) {
            f32x4 vv;
#pragma unroll
            for (int r = 0; r < 4; ++r) vv[r] = oacc[dn][r] * inv;
            *(u16x4*)(yab + base + dn * 16 + quad * 4) = pack4(vv);
        }
    }
}

// ---------------- k3: output projection (64x64 tiles, BK=64, dbuf) ---------
// grid (16, 64): n0 = bx*64, m0 = by*64. 256 thr / 4 waves; wave (wr,wc)
// owns 32x32 (acc[2][2]). LDS 32KB -> 4 blocks/CU x 4 waves = 16 waves/CU.
// 16 K-iters: per iter 4 gload16/thread, 8 b128 frag reads, 8 MFMA/wave,
// vmcnt(4) + 2 barriers. 8-slot XOR swizzle (qkv-verified).
__global__ __launch_bounds__(256) void proj_k(const u16* __restrict__ ya, const u16* __restrict__ Wpb,
                                              const float* __restrict__ bias, float* __restrict__ out) {
    __shared__ u16 As[2][4096];               // [buf][64][64] linear (content swizzled)
    __shared__ u16 Bs[2][4096];
    int tid = threadIdx.x;
    int n0 = blockIdx.x * 64, m0 = blockIdx.y * 64;
    int w = tid >> 6, lane = tid & 63, lr = lane & 15, quad = lane >> 4;
    int wr = w >> 1, wc = w & 1;
    f32x4 acc[2][2] = {};
    int srow = tid >> 3;                                  // staging row 0..31 (+32 second chunk)
    int swc8 = (((tid & 7) ^ (srow & 7)) << 3);           // pre-swizzled src col (u16)
    int soff = tid * 8;                                   // linear LDS u16 offset
    int lrx = lr & 7;                                     // fragment-read XOR key

#define PRJ_STAGE(bufi, kc) do {                                                     \
        gload16(ya  + (size_t)(m0 + srow) * C_EMB + (kc) + swc8,      &As[bufi][soff]);        \
        gload16(ya  + (size_t)(m0 + 32 + srow) * C_EMB + (kc) + swc8, &As[bufi][2048 + soff]); \
        gload16(Wpb + (size_t)(n0 + srow) * C_EMB + (kc) + swc8,      &Bs[bufi][soff]);        \
        gload16(Wpb + (size_t)(n0 + 32 + srow) * C_EMB + (kc) + swc8, &Bs[bufi][2048 + soff]); \
    } while (0)

    PRJ_STAGE(0, 0);
#pragma unroll 2
    for (int kt = 0; kt < 16; ++kt) {
        int cur = kt & 1;
        if (kt < 15) {
            PRJ_STAGE(cur ^ 1, (kt + 1) * 64);
            asm volatile("s_waitcnt vmcnt(4)" ::: "memory");
        } else {
            asm volatile("s_waitcnt vmcnt(0)" ::: "memory");
        }
        __builtin_amdgcn_s_barrier();
        asm volatile("" ::: "memory");
#pragma unroll
        for (int ks = 0; ks < 64; ks += 32) {
            int slot = (ks >> 3) + quad;                   // 0..7
            int rc8 = ((slot ^ lrx) << 3);                 // swizzled read col (u16)
            s16x8 af[2], bf[2];
#pragma unroll
            for (int i = 0; i < 2; ++i)
                af[i] = *(const s16x8*)&As[cur][(wr * 32 + i * 16 + lr) * 64 + rc8];
#pragma unroll
            for (int j = 0; j < 2; ++j)
                bf[j] = *(const s16x8*)&Bs[cur][(wc * 32 + j * 16 + lr) * 64 + rc8];
#pragma unroll
            for (int i = 0; i < 2; ++i)
#pragma unroll
                for (int j = 0; j < 2; ++j) acc[i][j] = MFMA16(af[i], bf[j], acc[i][j]);
        }
        asm volatile("" ::: "memory");
        __builtin_amdgcn_s_barrier();
    }
#undef PRJ_STAGE

    float bv[2];
#pragma unroll
    for (int j = 0; j < 2; ++j) bv[j] = bias[n0 + wc * 32 + j * 16 + lr];
#pragma unroll
    for (int i = 0; i < 2; ++i)
#pragma unroll
        for (int r = 0; r < 4; ++r) {
            int m = m0 + wr * 32 + i * 16 + quad * 4 + r;
#pragma unroll
            for (int j = 0; j < 2; ++j)
                out[(size_t)m * C_EMB + n0 + wc * 32 + j * 16 + lr] = acc[i][j][r] + bv[j];
        }
}

extern "C" void kernel_launch(void* const* d_in, const int* in_sizes, int n_in,
                              void* d_out, int out_size, void* d_ws, size_t ws_size,
                              hipStream_t stream) {
    // Inputs resolved BY ELEMENT COUNT (unique): x 4194304, W_attn 3145728,
    // b_attn 3072, W_proj 1048576, b_proj 1024. All fp32.
    const float *x = nullptr, *Wa = nullptr, *ba = nullptr, *Wp = nullptr, *bp = nullptr;
    for (int i = 0; i < n_in; ++i) {
        switch (in_sizes[i]) {
            case 4194304: x  = (const float*)d_in[i]; break;
            case 3145728: Wa = (const float*)d_in[i]; break;
            case 3072:    ba = (const float*)d_in[i]; break;
            case 1048576: Wp = (const float*)d_in[i]; break;
            case 1024:    bp = (const float*)d_in[i]; break;
            default: break;
        }
    }
    float* out = (float*)d_out;

    char* ws = (char*)d_ws;
    u16* qb     = (u16*)(ws);                    //  0.. 8 MiB  bf16 [B,H,T,D] (q*0.125*log2e)
    u16* kb     = (u16*)(ws + 8388608);          //  8..16 MiB  bf16 [B,H,T,D]
    u16* vt     = (u16*)(ws + 16777216);         // 16..24 MiB  bf16 [B,H,D,T]
    u16* yab    = (u16*)(ws + 25165824);         // 24..32 MiB  bf16 [B,T,C]
    float2* tab = (float2*)(ws + 33554432);      // 32..32.5 MiB
    u16* xb     = (u16*)(ws + 35651584);         // 34..42 MiB  bf16 [4096,1024]
    u16* Wab    = (u16*)(ws + 44040192);         // 42..48 MiB  bf16 [3072,1024]
    u16* Wpb    = (u16*)(ws + 50331648);         // 48..50 MiB  bf16 [1024,1024]

    prep_k<<<4352, 256, 0, stream>>>(x, Wa, Wp, xb, Wab, Wpb, tab);
    qkv_rope_k<<<dim3(24, 32), 256, 0, stream>>>(xb, Wab, ba, tab, qb, kb, vt);
    flash_k<<<dim3(32, 32), 256, 0, stream>>>(qb, kb, vt, yab);
    proj_k<<<dim3(16, 64), 256, 0, stream>>>(yab, Wpb, bp, out);
}

// Round 18
// 183.255 us; speedup vs baseline: 1.0311x; 1.0311x over previous
//
#include <hip/hip_runtime.h>

// B=2, T=2048, C=1024, H=16, D=64. Inputs fp32, OUTPUT fp32.
// Round 30 (post-mortem R29: m97 single-buf qkv REGRESSED +5us — vmcnt(0)
// drain every period lost to the 3-deep counted-vmcnt(8) pipeline; BK=64
// amortization didn't cover it. Lesson re-confirmed: counted vmcnt > bigger
// K-step for this tile):
//  - qkv_rope_k: REVERT to R18/R28 3-deep BK=32 pipeline verbatim
//    (3 buffers, stage kt+2, vmcnt(8) in-loop, 48KB LDS unions epilogue).
//  - prep_k / flash_k (R28 swizzled, 52.0us best) / proj_k (BK=64) unchanged.
// MFMA 16x16x32_bf16 layouts (HW-verified): A: m=lane&15,k=quad*8+j;
// B: k=quad*8+j,n=lane&15; C/D: col=lane&15,row=quad*4+reg.
// MFMA 16x16x16_bf16 (HW-verified R17): A: m=lane&15,k=quad*4+j;
// B: k=quad*4+j,n=lane&15; C/D: col=lane&15,row=quad*4+reg.

typedef unsigned short u16;
typedef u16 u16x4 __attribute__((ext_vector_type(4)));
typedef u16 u16x8 __attribute__((ext_vector_type(8)));
typedef short s16x4 __attribute__((ext_vector_type(4)));
typedef short s16x8 __attribute__((ext_vector_type(8)));
typedef float f32x4 __attribute__((ext_vector_type(4)));

#define T_SEQ 2048
#define C_EMB 1024
#define NH 16
#define HD 64

#define MFMA16(a, b, c) __builtin_amdgcn_mfma_f32_16x16x32_bf16(a, b, c, 0, 0, 0)

__device__ __forceinline__ f32x4 MFMA16K16(s16x4 a, s16x4 b, f32x4 c) {
#if __has_builtin(__builtin_amdgcn_mfma_f32_16x16x16bf16_1k)
    return __builtin_amdgcn_mfma_f32_16x16x16bf16_1k(a, b, c, 0, 0, 0);
#else
    asm("v_mfma_f32_16x16x16_bf16 %0, %1, %2, %0" : "+v"(c) : "v"(a), "v"(b));
    return c;
#endif
}

__device__ __forceinline__ u16 f2bf(float f) {
    union { float f; unsigned int i; } x; x.f = f;
    unsigned int r = x.i + 0x7fffu + ((x.i >> 16) & 1u);
    return (u16)(r >> 16);
}
__device__ __forceinline__ u16x4 pack4(f32x4 v) {
    u16x4 o;
#pragma unroll
    for (int j = 0; j < 4; ++j) o[j] = f2bf(v[j]);
    return o;
}
// hot-loop pack: HW packed convert (RNE), 2 instr per 4 values -> s16x4 frag
__device__ __forceinline__ s16x4 pack4cvt_s(f32x4 v) {
    union { s16x4 h; unsigned int w[2]; } u;
    asm("v_cvt_pk_bf16_f32 %0, %1, %2" : "=v"(u.w[0]) : "v"(v[0]), "v"(v[1]));
    asm("v_cvt_pk_bf16_f32 %0, %1, %2" : "=v"(u.w[1]) : "v"(v[2]), "v"(v[3]));
    return u.h;
}
// async global->LDS, 16B per lane (dest must be wave-uniform base + lane*16)
__device__ __forceinline__ void gload16(const void* g, void* l) {
    __builtin_amdgcn_global_load_lds(
        (const __attribute__((address_space(1))) unsigned int*)g,
        (__attribute__((address_space(3))) unsigned int*)l, 16, 0, 0);
}

// ---------------- k0: merged prep (3x fp32->bf16 conv + rope tables) -------
// grid 4352: [0,2048) conv x; [2048,3584) conv Wa; [3584,4096) conv Wp;
// [4096,4352) rope tables. All sections exact-sized (no bounds checks).
__global__ __launch_bounds__(256) void prep_k(const float* __restrict__ x, const float* __restrict__ Wa,
                                              const float* __restrict__ Wp,
                                              u16* __restrict__ xb, u16* __restrict__ Wab,
                                              u16* __restrict__ Wpb, float2* __restrict__ tab) {
    int bid = blockIdx.x, tid = threadIdx.x;
    if (bid < 4096) {
        const float* src;
        u16* dst;
        int i;
        if (bid < 2048)      { src = x;  dst = xb;  i = bid * 256 + tid; }
        else if (bid < 3584) { src = Wa; dst = Wab; i = (bid - 2048) * 256 + tid; }
        else                 { src = Wp; dst = Wpb; i = (bid - 3584) * 256 + tid; }
        f32x4 a = ((const f32x4*)src)[i * 2];
        f32x4 b = ((const f32x4*)src)[i * 2 + 1];
        u16x8 o;
#pragma unroll
        for (int j = 0; j < 4; ++j) o[j] = f2bf(a[j]);
#pragma unroll
        for (int j = 0; j < 4; ++j) o[4 + j] = f2bf(b[j]);
        ((u16x8*)dst)[i] = o;
    } else {
        int idx = (bid - 4096) * 256 + tid;   // 65536 = T*32
        int t = idx >> 5, j = idx & 31;
        float inv = __builtin_exp2f(-0.41524101186092f * (float)j);  // 10000^(-j/32)
        float s_, c_;
        sincosf((float)t * inv, &s_, &c_);
        tab[idx] = make_float2(c_, s_);
    }
}

// ---------------- k1: QKV GEMM + RoPE (gload_lds, BK=32, 3-deep pipeline) --
// grid (24, 32): n0 = bx*128 (0..3071), m0 = by*128 (0..4095)
__global__ __launch_bounds__(256) void qkv_rope_k(const u16* __restrict__ xb, const u16* __restrict__ Wab,
                                                  const float* __restrict__ bias,
                                                  const float2* __restrict__ tab,
                                                  u16* __restrict__ qb, u16* __restrict__ kb,
                                                  u16* __restrict__ vt) {
    __shared__ u16 smem[24576];               // As[3][4096] | Bs[3][4096] = 48KB; Ct[17408] unions
    u16* As = smem;                           // [buf][128][32] linear (content swizzled)
    u16* Bs = smem + 12288;
    int tid = threadIdx.x;
    int n0 = blockIdx.x * 128, m0 = blockIdx.y * 128;
    int w = tid >> 6, lane = tid & 63, lr = lane & 15, quad = lane >> 4;
    int wr = w >> 1, wc = w & 1;
    f32x4 acc[4][4] = {};
    int srow = tid >> 2;                                  // staging row 0..63 (+64 second half)
    int swc8 = (((tid & 3) ^ (srow & 3)) << 3);           // pre-swizzled src col (u16)
    int soff = tid * 8;                                   // linear LDS u16 offset
    int rc8 = ((quad ^ (lr & 3)) << 3);                   // swizzled fragment-read col

#define QKV_STAGE(bufi, kc) do {                                                   \
        int _b = (bufi) * 4096;                                                    \
        gload16(xb  + (size_t)(m0 + srow) * C_EMB + (kc) + swc8,      &As[_b + soff]);        \
        gload16(xb  + (size_t)(m0 + 64 + srow) * C_EMB + (kc) + swc8, &As[_b + 2048 + soff]); \
        gload16(Wab + (size_t)(n0 + srow) * C_EMB + (kc) + swc8,      &Bs[_b + soff]);        \
        gload16(Wab + (size_t)(n0 + 64 + srow) * C_EMB + (kc) + swc8, &Bs[_b + 2048 + soff]); \
    } while (0)

    QKV_STAGE(0, 0);
    QKV_STAGE(1, 32);
    int cur = 0;
    for (int kt = 0; kt < 32; ++kt) {
        if (kt < 30) {
            int nb = cur + 2; if (nb >= 3) nb -= 3;
            QKV_STAGE(nb, (kt + 2) * 32);
            asm volatile("s_waitcnt vmcnt(8)" ::: "memory");   // tile-kt loads done
        } else if (kt == 30) {
            asm volatile("s_waitcnt vmcnt(4)" ::: "memory");
        } else {
            asm volatile("s_waitcnt vmcnt(0)" ::: "memory");
        }
        __builtin_amdgcn_s_barrier();
        asm volatile("" ::: "memory");
        int cb = cur * 4096;
        s16x8 af[4], bf[4];
#pragma unroll
        for (int i = 0; i < 4; ++i)
            af[i] = *(const s16x8*)&As[cb + (wr * 64 + i * 16 + lr) * 32 + rc8];
#pragma unroll
        for (int j = 0; j < 4; ++j)
            bf[j] = *(const s16x8*)&Bs[cb + (wc * 64 + j * 16 + lr) * 32 + rc8];
#pragma unroll
        for (int i = 0; i < 4; ++i)
#pragma unroll
            for (int j = 0; j < 4; ++j) acc[i][j] = MFMA16(af[i], bf[j], acc[i][j]);
        asm volatile("" ::: "memory");
        __builtin_amdgcn_s_barrier();
        cur = cur + 1; if (cur >= 3) cur -= 3;
    }
#undef QKV_STAGE

    int sec = n0 >> 10;                       // 0=q 1=k 2=v (blocks never straddle)
    float bv[4];
#pragma unroll
    for (int j = 0; j < 4; ++j) bv[j] = bias[n0 + wc * 64 + j * 16 + lr];

    int h0 = (n0 & 1023) >> 6;
    int b = m0 >> 11, tbase = m0 & 2047;
    if (sec == 2) {
        // C tile (+bias) -> LDS [d][m] (136-padded) -> coalesced 16B
        // transposed stores to vt[((b*16+h)*64+d)*2048 + t].
        u16* Ct = smem;                        // 128 x 136 u16 = 34816 B
#pragma unroll
        for (int i = 0; i < 4; ++i)
#pragma unroll
            for (int j = 0; j < 4; ++j) {
                f32x4 vv;
#pragma unroll
                for (int r = 0; r < 4; ++r) vv[r] = acc[i][j][r] + bv[j];
                int d = wc * 64 + j * 16 + lr;
                int m4 = wr * 64 + i * 16 + quad * 4;
                *(u16x4*)&Ct[d * 136 + m4] = pack4(vv);
            }
        __syncthreads();
        size_t hb = (size_t)(b * NH);
#pragma unroll
        for (int p = 0; p < 8; ++p) {
            int idx = p * 256 + tid;
            int d = idx >> 4, mc = (idx & 15) << 3;
            s16x8 vdat = *(const s16x8*)&Ct[d * 136 + mc];
            int h = h0 + (d >> 6), dd = d & 63;
            *(s16x8*)(vt + ((hb + h) * HD + dd) * T_SEQ + tbase + mc) = vdat;
        }
    } else {
        // q/k: RoPE in-register, stage [m][n] in LDS, coalesced b128 stores.
        u16* dst = (sec == 0) ? qb : kb;
        // fold 1/sqrt(D) AND log2(e) into q so flash softmax is native base-2:
        float qs = (sec == 0) ? 0.18033688011112043f : 1.0f;
        u16* Ct = smem;                        // 128 x 136 u16
        __syncthreads();                       // all frag reads done before overwrite
#pragma unroll
        for (int i = 0; i < 4; ++i)
#pragma unroll
            for (int r = 0; r < 4; ++r) {
                int mrow = wr * 64 + i * 16 + quad * 4 + r;
                int t = (m0 + mrow) & 2047;
#pragma unroll
                for (int j = 0; j < 2; ++j) {
                    int d1 = j * 16 + lr;                 // 0..31; partner +32 in tile j+2
                    float2 cs = tab[t * 32 + d1];
                    float v1 = acc[i][j][r] + bv[j];
                    float v2 = acc[i][j + 2][r] + bv[j + 2];
                    int n1 = wc * 64 + j * 16 + lr;
                    Ct[mrow * 136 + n1]      = f2bf((v1 * cs.x - v2 * cs.y) * qs);
                    Ct[mrow * 136 + n1 + 32] = f2bf((v2 * cs.x + v1 * cs.y) * qs);
                }
            }
        __syncthreads();
#pragma unroll
        for (int p = 0; p < 8; ++p) {
            int idx = p * 256 + tid;              // 128 rows x 16 chunks of 8 u16
            int mrow = idx >> 4, c = idx & 15;
            s16x8 vdat = *(const s16x8*)&Ct[mrow * 136 + c * 8];
            int h = h0 + (c >> 3), dd = (c & 7) << 3;
            *(s16x8*)(dst + ((size_t)(b * NH + h) * T_SEQ + tbase + mrow) * HD + dd) = vdat;
        }
    }
}

// ---------------- k2: flash attention (64-row Q tile, XOR-swizzled LDS) ----
// grid (32, 32), 256 threads / 4 waves / 1 strip each. qt = q-tile of 64
// rows; wave w owns rows [qt*64+16w, +16). 1024 blocks = whole grid
// co-resident at 4 blocks/CU (LDS 32KB). Mask only on kt==qt.
// K/V LDS: [64][64] linear, 8-slot XOR swizzle LDS[row][s]=G[row][s^(row&7)]
// (reg-staged writes swizzle the LDS addr). ak slot=(ks*4+quad)^(lr&7);
// av slot=(2tc+(quad>>1))^(lr&7), +4 u16 if quad odd. All bank-uniform.
// S^T: elem (k'=k0+tc*16+quad*4+r, q=rbase+lr). PV: 16x16x16, P in regs.
// Double-buffered K/V, one barrier per k-tile. T5 setprio around MFMAs.
__global__ __launch_bounds__(256, 4) void flash_k(const u16* __restrict__ qb, const u16* __restrict__ kb,
                                                  const u16* __restrict__ vt, u16* __restrict__ yab) {
    __shared__ u16 Ks[2][64 * 64];
    __shared__ u16 Vs[2][64 * 64];
    int tid = threadIdx.x;
    int bx = blockIdx.x, by = blockIdx.y;
    int qt = (by < 16) ? (31 - bx) : bx;      // complementary pairing for balance
    int bh = by;
    int w = tid >> 6, lane = tid & 63, lr = lane & 15, quad = lane >> 4;
    int q0 = qt * 64;
    const u16* qh = qb + (size_t)bh * T_SEQ * HD;
    const u16* kh = kb + (size_t)bh * T_SEQ * HD;
    const u16* vh = vt + (size_t)bh * HD * T_SEQ;

    int rbase = q0 + w * 16;                  // this wave's strip

    s16x8 aq[2];                              // B-frag of Q (n=q-row=lr, k=d)
#pragma unroll
    for (int ks = 0; ks < 2; ++ks)
        aq[ks] = *(const s16x8*)(qh + (size_t)(rbase + lr) * HD + ks * 32 + quad * 8);

    int srow = tid >> 3, sc8 = (tid & 7) << 3;       // staging: rows srow, srow+32
    int swsl = (((tid & 7) ^ (srow & 7)) << 3);      // swizzled LDS write col (u16)
    int lrx8 = (lr & 7) << 3;                        // fragment-read XOR key (u16 units)

    float m_i = -1e30f;
    f32x4 l4 = {0.f, 0.f, 0.f, 0.f};          // per-lane l partials
    f32x4 oacc[4] = {};                       // O^T: elem (d=dn*16+quad*4+r, q=lr)

    int ktmax = qt;
    {   // prologue: stage tile 0 into buffer 0 (2 K-rows + 2 V-rows / thread)
        s16x8 ka = *(const s16x8*)(kh + (size_t)srow * HD + sc8);
        s16x8 kb2 = *(const s16x8*)(kh + (size_t)(srow + 32) * HD + sc8);
        s16x8 va = *(const s16x8*)(vh + (size_t)srow * T_SEQ + sc8);
        s16x8 vb = *(const s16x8*)(vh + (size_t)(srow + 32) * T_SEQ + sc8);
        *(s16x8*)&Ks[0][srow * 64 + swsl] = ka;
        *(s16x8*)&Ks[0][(srow + 32) * 64 + swsl] = kb2;
        *(s16x8*)&Vs[0][srow * 64 + swsl] = va;
        *(s16x8*)&Vs[0][(srow + 32) * 64 + swsl] = vb;
    }
    __syncthreads();

    for (int kt = 0; kt <= ktmax; ++kt) {
        int cur = kt & 1;
        int k0 = kt * 64;
        bool pf = kt < ktmax;
        s16x8 kr0, kr1, vr0, vr1;             // next-tile prefetch registers
        if (pf) {
            int kn = k0 + 64;
            kr0 = *(const s16x8*)(kh + (size_t)(kn + srow) * HD + sc8);
            kr1 = *(const s16x8*)(kh + (size_t)(kn + srow + 32) * HD + sc8);
            vr0 = *(const s16x8*)(vh + (size_t)srow * T_SEQ + kn + sc8);
            vr1 = *(const s16x8*)(vh + (size_t)(srow + 32) * T_SEQ + kn + sc8);
        }
        const u16* Kc = Ks[cur];
        const u16* Vc = Vs[cur];

        // fragments (all strips active every tile in the 64-row form)
        s16x8 ak[2][4];                       // K frag (m=k-row=lr, k=d)
#pragma unroll
        for (int ks = 0; ks < 2; ++ks)
#pragma unroll
            for (int tc = 0; tc < 4; ++tc)
                ak[ks][tc] = *(const s16x8*)&Kc[(tc * 16 + lr) * 64 + (((ks * 4 + quad) << 3) ^ lrx8)];
        s16x4 av[4][4];                       // V^T frag (m=d=dn*16+lr, k=tc*16+quad*4+j)
#pragma unroll
        for (int dn = 0; dn < 4; ++dn) {
            const u16* vrow = &Vc[(dn * 16 + lr) * 64 + ((quad & 1) << 2)];
#pragma unroll
            for (int tc = 0; tc < 4; ++tc)
                av[dn][tc] = *(const s16x4*)(vrow + ((((tc << 1) + (quad >> 1)) << 3) ^ lrx8));
        }
        f32x4 sacc[4] = {};
        __builtin_amdgcn_s_setprio(1);        // T5: favor MFMA wave
#pragma unroll
        for (int ks = 0; ks < 2; ++ks)
#pragma unroll
            for (int tc = 0; tc < 4; ++tc) sacc[tc] = MFMA16(ak[ks][tc], aq[ks], sacc[tc]);
        __builtin_amdgcn_s_setprio(0);
        if (kt == ktmax) {                    // diagonal tile: causal mask
#pragma unroll
            for (int tc = 0; tc < 4; ++tc)
#pragma unroll
                for (int r = 0; r < 4; ++r)
                    if (k0 + tc * 16 + quad * 4 + r > rbase + lr) sacc[tc][r] = -1e30f;
        }
        // per-lane local max; __all == row-max guard
        f32x4 mv = sacc[0];
#pragma unroll
        for (int tc = 1; tc < 4; ++tc)
#pragma unroll
            for (int r = 0; r < 4; ++r) mv[r] = fmaxf(mv[r], sacc[tc][r]);
        float loc = fmaxf(fmaxf(mv[0], mv[1]), fmaxf(mv[2], mv[3]));
        bool need = !__all(loc <= m_i + 8.0f);   // defer-max (T13, THR=8)
        float alpha = 1.0f;
        if (need) {                            // rare: full cross-lane max
            float mx = fmaxf(loc, __shfl_xor(loc, 16, 64));
            mx = fmaxf(mx, __shfl_xor(mx, 32, 64));
            float mn = fmaxf(m_i, mx);
            alpha = __builtin_exp2f(m_i - mn);
            m_i = mn;
#pragma unroll
            for (int r = 0; r < 4; ++r) l4[r] *= alpha;
        }
        float mnow = m_i;
#pragma unroll
        for (int tc = 0; tc < 4; ++tc)
#pragma unroll
            for (int r = 0; r < 4; ++r) {
                float p = __builtin_exp2f(sacc[tc][r] - mnow);
                sacc[tc][r] = p;
                l4[r] += p;                    // per-lane partial; folded at end
            }
        // P in registers: pack4cvt(sacc[tc]) IS the 16x16x16 B-frag
        s16x4 pa[4];
#pragma unroll
        for (int tc = 0; tc < 4; ++tc) pa[tc] = pack4cvt_s(sacc[tc]);
        if (need) {
#pragma unroll
            for (int dn = 0; dn < 4; ++dn)
#pragma unroll
                for (int r = 0; r < 4; ++r) oacc[dn][r] *= alpha;
        }
        __builtin_amdgcn_s_setprio(1);        // T5: favor MFMA wave
#pragma unroll
        for (int dn = 0; dn < 4; ++dn)
#pragma unroll
            for (int tc = 0; tc < 4; ++tc)
                oacc[dn] = MFMA16K16(av[dn][tc], pa[tc], oacc[dn]);
        __builtin_amdgcn_s_setprio(0);

        if (pf) {                              // write prefetched tile to other buffer
            int nx = cur ^ 1;
            *(s16x8*)&Ks[nx][srow * 64 + swsl] = kr0;
            *(s16x8*)&Ks[nx][(srow + 32) * 64 + swsl] = kr1;
            *(s16x8*)&Vs[nx][srow * 64 + swsl] = vr0;
            *(s16x8*)&Vs[nx][(srow + 32) * 64 + swsl] = vr1;
        }
        __syncthreads();                       // single barrier per k-tile
    }
    // fold l partials: 4 per-lane + the 4 lanes of each row (xor 16, 32)
    float rs = (l4[0] + l4[1]) + (l4[2] + l4[3]);
    rs += __shfl_xor(rs, 16, 64);
    rs += __shfl_xor(rs, 32, 64);
    int b = bh >> 4, hh = bh & 15;
    {
        float inv = 1.f / rs;
        int t = rbase + lr;
        size_t base = ((size_t)b * T_SEQ + t) * C_EMB + hh * HD;
#pragma unroll
        for (int dn = 0; dn < 4; ++dn) {
            f32x4 vv;
#pragma unroll
            for (int r = 0; r < 4; ++r) vv[r] = oacc[dn][r] * inv;
            *(u16x4*)(yab + base + dn * 16 + quad * 4) = pack4(vv);
        }
    }
}

// ---------------- k3: output projection (64x64 tiles, BK=64, dbuf) ---------
// grid (16, 64): n0 = bx*64, m0 = by*64. 256 thr / 4 waves; wave (wr,wc)
// owns 32x32 (acc[2][2]). LDS 32KB -> 4 blocks/CU x 4 waves = 16 waves/CU.
// 16 K-iters: per iter 4 gload16/thread, 8 b128 frag reads, 8 MFMA/wave,
// vmcnt(4) + 2 barriers. 8-slot XOR swizzle (qkv-verified).
__global__ __launch_bounds__(256) void proj_k(const u16* __restrict__ ya, const u16* __restrict__ Wpb,
                                              const float* __restrict__ bias, float* __restrict__ out) {
    __shared__ u16 As[2][4096];               // [buf][64][64] linear (content swizzled)
    __shared__ u16 Bs[2][4096];
    int tid = threadIdx.x;
    int n0 = blockIdx.x * 64, m0 = blockIdx.y * 64;
    int w = tid >> 6, lane = tid & 63, lr = lane & 15, quad = lane >> 4;
    int wr = w >> 1, wc = w & 1;
    f32x4 acc[2][2] = {};
    int srow = tid >> 3;                                  // staging row 0..31 (+32 second chunk)
    int swc8 = (((tid & 7) ^ (srow & 7)) << 3);           // pre-swizzled src col (u16)
    int soff = tid * 8;                                   // linear LDS u16 offset
    int lrx = lr & 7;                                     // fragment-read XOR key

#define PRJ_STAGE(bufi, kc) do {                                                     \
        gload16(ya  + (size_t)(m0 + srow) * C_EMB + (kc) + swc8,      &As[bufi][soff]);        \
        gload16(ya  + (size_t)(m0 + 32 + srow) * C_EMB + (kc) + swc8, &As[bufi][2048 + soff]); \
        gload16(Wpb + (size_t)(n0 + srow) * C_EMB + (kc) + swc8,      &Bs[bufi][soff]);        \
        gload16(Wpb + (size_t)(n0 + 32 + srow) * C_EMB + (kc) + swc8, &Bs[bufi][2048 + soff]); \
    } while (0)

    PRJ_STAGE(0, 0);
#pragma unroll 2
    for (int kt = 0; kt < 16; ++kt) {
        int cur = kt & 1;
        if (kt < 15) {
            PRJ_STAGE(cur ^ 1, (kt + 1) * 64);
            asm volatile("s_waitcnt vmcnt(4)" ::: "memory");
        } else {
            asm volatile("s_waitcnt vmcnt(0)" ::: "memory");
        }
        __builtin_amdgcn_s_barrier();
        asm volatile("" ::: "memory");
#pragma unroll
        for (int ks = 0; ks < 64; ks += 32) {
            int slot = (ks >> 3) + quad;                   // 0..7
            int rc8 = ((slot ^ lrx) << 3);                 // swizzled read col (u16)
            s16x8 af[2], bf[2];
#pragma unroll
            for (int i = 0; i < 2; ++i)
                af[i] = *(const s16x8*)&As[cur][(wr * 32 + i * 16 + lr) * 64 + rc8];
#pragma unroll
            for (int j = 0; j < 2; ++j)
                bf[j] = *(const s16x8*)&Bs[cur][(wc * 32 + j * 16 + lr) * 64 + rc8];
#pragma unroll
            for (int i = 0; i < 2; ++i)
#pragma unroll
                for (int j = 0; j < 2; ++j) acc[i][j] = MFMA16(af[i], bf[j], acc[i][j]);
        }
        asm volatile("" ::: "memory");
        __builtin_amdgcn_s_barrier();
    }
#undef PRJ_STAGE

    float bv[2];
#pragma unroll
    for (int j = 0; j < 2; ++j) bv[j] = bias[n0 + wc * 32 + j * 16 + lr];
#pragma unroll
    for (int i = 0; i < 2; ++i)
#pragma unroll
        for (int r = 0; r < 4; ++r) {
            int m = m0 + wr * 32 + i * 16 + quad * 4 + r;
#pragma unroll
            for (int j = 0; j < 2; ++j)
                out[(size_t)m * C_EMB + n0 + wc * 32 + j * 16 + lr] = acc[i][j][r] + bv[j];
        }
}

extern "C" void kernel_launch(void* const* d_in, const int* in_sizes, int n_in,
                              void* d_out, int out_size, void* d_ws, size_t ws_size,
                              hipStream_t stream) {
    // Inputs resolved BY ELEMENT COUNT (unique): x 4194304, W_attn 3145728,
    // b_attn 3072, W_proj 1048576, b_proj 1024. All fp32.
    const float *x = nullptr, *Wa = nullptr, *ba = nullptr, *Wp = nullptr, *bp = nullptr;
    for (int i = 0; i < n_in; ++i) {
        switch (in_sizes[i]) {
            case 4194304: x  = (const float*)d_in[i]; break;
            case 3145728: Wa = (const float*)d_in[i]; break;
            case 3072:    ba = (const float*)d_in[i]; break;
            case 1048576: Wp = (const float*)d_in[i]; break;
            case 1024:    bp = (const float*)d_in[i]; break;
            default: break;
        }
    }
    float* out = (float*)d_out;

    char* ws = (char*)d_ws;
    u16* qb     = (u16*)(ws);                    //  0.. 8 MiB  bf16 [B,H,T,D] (q*0.125*log2e)
    u16* kb     = (u16*)(ws + 8388608);          //  8..16 MiB  bf16 [B,H,T,D]
    u16* vt     = (u16*)(ws + 16777216);         // 16..24 MiB  bf16 [B,H,D,T]
    u16* yab    = (u16*)(ws + 25165824);         // 24..32 MiB  bf16 [B,T,C]
    float2* tab = (float2*)(ws + 33554432);      // 32..32.5 MiB
    u16* xb     = (u16*)(ws + 35651584);         // 34..42 MiB  bf16 [4096,1024]
    u16* Wab    = (u16*)(ws + 44040192);         // 42..48 MiB  bf16 [3072,1024]
    u16* Wpb    = (u16*)(ws + 50331648);         // 48..50 MiB  bf16 [1024,1024]

    prep_k<<<4352, 256, 0, stream>>>(x, Wa, Wp, xb, Wab, Wpb, tab);
    qkv_rope_k<<<dim3(24, 32), 256, 0, stream>>>(xb, Wab, ba, tab, qb, kb, vt);
    flash_k<<<dim3(32, 32), 256, 0, stream>>>(qb, kb, vt, yab);
    proj_k<<<dim3(16, 64), 256, 0, stream>>>(yab, Wpb, bp, out);
}

// Round 19
// 182.007 us; speedup vs baseline: 1.0382x; 1.0069x over previous
//
#include <hip/hip_runtime.h>

// B=2, T=2048, C=1024, H=16, D=64. Inputs fp32, OUTPUT fp32.
// Round 31 (post-mortem R30: revert banked 183.3 best; top-5 shows qkv ~55.7
// co-leading with flash. qkv is latency-bound at 12 waves/CU (MfmaUtil ~16).
// Apply the R14 lesson (same tile, 2x waves, thinner per-wave slice):
//  - qkv_rope_k: 512 threads / 8 waves (4x2 wave grid, acc[2][4], 32 VGPR
//    accumulator), staging = 2 gloads/thread covering the full 16KB
//    tile-pair, 3-deep pipeline with vmcnt(4)/(2)/(0). 24 waves/CU (2x).
//    Epilogue re-indexed for 512 thr (4 copy passes).
//  - prep_k / flash_k / proj_k unchanged from R30.
// MFMA 16x16x32_bf16 layouts (HW-verified): A: m=lane&15,k=quad*8+j;
// B: k=quad*8+j,n=lane&15; C/D: col=lane&15,row=quad*4+reg.
// MFMA 16x16x16_bf16 (HW-verified R17): A: m=lane&15,k=quad*4+j;
// B: k=quad*4+j,n=lane&15; C/D: col=lane&15,row=quad*4+reg.

typedef unsigned short u16;
typedef u16 u16x4 __attribute__((ext_vector_type(4)));
typedef u16 u16x8 __attribute__((ext_vector_type(8)));
typedef short s16x4 __attribute__((ext_vector_type(4)));
typedef short s16x8 __attribute__((ext_vector_type(8)));
typedef float f32x4 __attribute__((ext_vector_type(4)));

#define T_SEQ 2048
#define C_EMB 1024
#define NH 16
#define HD 64

#define MFMA16(a, b, c) __builtin_amdgcn_mfma_f32_16x16x32_bf16(a, b, c, 0, 0, 0)

__device__ __forceinline__ f32x4 MFMA16K16(s16x4 a, s16x4 b, f32x4 c) {
#if __has_builtin(__builtin_amdgcn_mfma_f32_16x16x16bf16_1k)
    return __builtin_amdgcn_mfma_f32_16x16x16bf16_1k(a, b, c, 0, 0, 0);
#else
    asm("v_mfma_f32_16x16x16_bf16 %0, %1, %2, %0" : "+v"(c) : "v"(a), "v"(b));
    return c;
#endif
}

__device__ __forceinline__ u16 f2bf(float f) {
    union { float f; unsigned int i; } x; x.f = f;
    unsigned int r = x.i + 0x7fffu + ((x.i >> 16) & 1u);
    return (u16)(r >> 16);
}
__device__ __forceinline__ u16x4 pack4(f32x4 v) {
    u16x4 o;
#pragma unroll
    for (int j = 0; j < 4; ++j) o[j] = f2bf(v[j]);
    return o;
}
// hot-loop pack: HW packed convert (RNE), 2 instr per 4 values -> s16x4 frag
__device__ __forceinline__ s16x4 pack4cvt_s(f32x4 v) {
    union { s16x4 h; unsigned int w[2]; } u;
    asm("v_cvt_pk_bf16_f32 %0, %1, %2" : "=v"(u.w[0]) : "v"(v[0]), "v"(v[1]));
    asm("v_cvt_pk_bf16_f32 %0, %1, %2" : "=v"(u.w[1]) : "v"(v[2]), "v"(v[3]));
    return u.h;
}
// async global->LDS, 16B per lane (dest must be wave-uniform base + lane*16)
__device__ __forceinline__ void gload16(const void* g, void* l) {
    __builtin_amdgcn_global_load_lds(
        (const __attribute__((address_space(1))) unsigned int*)g,
        (__attribute__((address_space(3))) unsigned int*)l, 16, 0, 0);
}

// ---------------- k0: merged prep (3x fp32->bf16 conv + rope tables) -------
// grid 4352: [0,2048) conv x; [2048,3584) conv Wa; [3584,4096) conv Wp;
// [4096,4352) rope tables. All sections exact-sized (no bounds checks).
__global__ __launch_bounds__(256) void prep_k(const float* __restrict__ x, const float* __restrict__ Wa,
                                              const float* __restrict__ Wp,
                                              u16* __restrict__ xb, u16* __restrict__ Wab,
                                              u16* __restrict__ Wpb, float2* __restrict__ tab) {
    int bid = blockIdx.x, tid = threadIdx.x;
    if (bid < 4096) {
        const float* src;
        u16* dst;
        int i;
        if (bid < 2048)      { src = x;  dst = xb;  i = bid * 256 + tid; }
        else if (bid < 3584) { src = Wa; dst = Wab; i = (bid - 2048) * 256 + tid; }
        else                 { src = Wp; dst = Wpb; i = (bid - 3584) * 256 + tid; }
        f32x4 a = ((const f32x4*)src)[i * 2];
        f32x4 b = ((const f32x4*)src)[i * 2 + 1];
        u16x8 o;
#pragma unroll
        for (int j = 0; j < 4; ++j) o[j] = f2bf(a[j]);
#pragma unroll
        for (int j = 0; j < 4; ++j) o[4 + j] = f2bf(b[j]);
        ((u16x8*)dst)[i] = o;
    } else {
        int idx = (bid - 4096) * 256 + tid;   // 65536 = T*32
        int t = idx >> 5, j = idx & 31;
        float inv = __builtin_exp2f(-0.41524101186092f * (float)j);  // 10000^(-j/32)
        float s_, c_;
        sincosf((float)t * inv, &s_, &c_);
        tab[idx] = make_float2(c_, s_);
    }
}

// ---------------- k1: QKV GEMM + RoPE (512 thr, BK=32, 3-deep pipeline) ----
// grid (24, 32): n0 = bx*128 (0..3071), m0 = by*128 (0..4095).
// 8 waves (4x2): wave (wr,wc) owns rows wr*32..+32, cols wc*64..+64
// (acc[2][4]). Staging: 2 gloads/thread = full 16KB A+B tile pair.
// 24 waves/CU (3 blocks x 8). 4-slot XOR swizzle (R18-verified).
__global__ __launch_bounds__(512) void qkv_rope_k(const u16* __restrict__ xb, const u16* __restrict__ Wab,
                                                  const float* __restrict__ bias,
                                                  const float2* __restrict__ tab,
                                                  u16* __restrict__ qb, u16* __restrict__ kb,
                                                  u16* __restrict__ vt) {
    __shared__ u16 smem[24576];               // As[3][4096] | Bs[3][4096] = 48KB; Ct[17408] unions
    u16* As = smem;                           // [buf][128][32] linear (content swizzled)
    u16* Bs = smem + 12288;
    int tid = threadIdx.x;
    int n0 = blockIdx.x * 128, m0 = blockIdx.y * 128;
    int w = tid >> 6, lane = tid & 63, lr = lane & 15, quad = lane >> 4;
    int wr = w >> 1, wc = w & 1;              // 4x2 wave grid
    f32x4 acc[2][4] = {};
    int srow = tid >> 2;                                  // staging row 0..127
    int swc8 = (((tid & 3) ^ (srow & 3)) << 3);           // pre-swizzled src col (u16)
    int soff = tid * 8;                                   // linear LDS u16 offset
    int rc8 = ((quad ^ (lr & 3)) << 3);                   // swizzled fragment-read col

#define QKV_STAGE(bufi, kc) do {                                              \
        int _b = (bufi) * 4096;                                               \
        gload16(xb  + (size_t)(m0 + srow) * C_EMB + (kc) + swc8, &As[_b + soff]); \
        gload16(Wab + (size_t)(n0 + srow) * C_EMB + (kc) + swc8, &Bs[_b + soff]); \
    } while (0)

    QKV_STAGE(0, 0);
    QKV_STAGE(1, 32);
    int cur = 0;
    for (int kt = 0; kt < 32; ++kt) {
        if (kt < 30) {
            int nb = cur + 2; if (nb >= 3) nb -= 3;
            QKV_STAGE(nb, (kt + 2) * 32);
            asm volatile("s_waitcnt vmcnt(4)" ::: "memory");   // tile-kt loads done
        } else if (kt == 30) {
            asm volatile("s_waitcnt vmcnt(2)" ::: "memory");
        } else {
            asm volatile("s_waitcnt vmcnt(0)" ::: "memory");
        }
        __builtin_amdgcn_s_barrier();
        asm volatile("" ::: "memory");
        int cb = cur * 4096;
        s16x8 af[2], bf[4];
#pragma unroll
        for (int i = 0; i < 2; ++i)
            af[i] = *(const s16x8*)&As[cb + (wr * 32 + i * 16 + lr) * 32 + rc8];
#pragma unroll
        for (int j = 0; j < 4; ++j)
            bf[j] = *(const s16x8*)&Bs[cb + (wc * 64 + j * 16 + lr) * 32 + rc8];
#pragma unroll
        for (int i = 0; i < 2; ++i)
#pragma unroll
            for (int j = 0; j < 4; ++j) acc[i][j] = MFMA16(af[i], bf[j], acc[i][j]);
        asm volatile("" ::: "memory");
        __builtin_amdgcn_s_barrier();
        cur = cur + 1; if (cur >= 3) cur -= 3;
    }
#undef QKV_STAGE

    int sec = n0 >> 10;                       // 0=q 1=k 2=v (blocks never straddle)
    float bv[4];
#pragma unroll
    for (int j = 0; j < 4; ++j) bv[j] = bias[n0 + wc * 64 + j * 16 + lr];

    int h0 = (n0 & 1023) >> 6;
    int b = m0 >> 11, tbase = m0 & 2047;
    if (sec == 2) {
        // C tile (+bias) -> LDS [d][m] (136-padded) -> coalesced 16B
        // transposed stores to vt[((b*16+h)*64+d)*2048 + t].
        u16* Ct = smem;                        // 128 x 136 u16 = 34816 B
        __syncthreads();                       // frag reads done before overwrite
#pragma unroll
        for (int i = 0; i < 2; ++i)
#pragma unroll
            for (int j = 0; j < 4; ++j) {
                f32x4 vv;
#pragma unroll
                for (int r = 0; r < 4; ++r) vv[r] = acc[i][j][r] + bv[j];
                int d = wc * 64 + j * 16 + lr;
                int m4 = wr * 32 + i * 16 + quad * 4;
                *(u16x4*)&Ct[d * 136 + m4] = pack4(vv);
            }
        __syncthreads();
        size_t hb = (size_t)(b * NH);
#pragma unroll
        for (int p = 0; p < 4; ++p) {
            int idx = p * 512 + tid;
            int d = idx >> 4, mc = (idx & 15) << 3;
            s16x8 vdat = *(const s16x8*)&Ct[d * 136 + mc];
            int h = h0 + (d >> 6), dd = d & 63;
            *(s16x8*)(vt + ((hb + h) * HD + dd) * T_SEQ + tbase + mc) = vdat;
        }
    } else {
        // q/k: RoPE in-register, stage [m][n] in LDS, coalesced b128 stores.
        u16* dst = (sec == 0) ? qb : kb;
        // fold 1/sqrt(D) AND log2(e) into q so flash softmax is native base-2:
        float qs = (sec == 0) ? 0.18033688011112043f : 1.0f;
        u16* Ct = smem;                        // 128 x 136 u16
        __syncthreads();                       // all frag reads done before overwrite
#pragma unroll
        for (int i = 0; i < 2; ++i)
#pragma unroll
            for (int r = 0; r < 4; ++r) {
                int mrow = wr * 32 + i * 16 + quad * 4 + r;
                int t = (m0 + mrow) & 2047;
#pragma unroll
                for (int j = 0; j < 2; ++j) {
                    int d1 = j * 16 + lr;                 // 0..31; partner +32 in tile j+2
                    float2 cs = tab[t * 32 + d1];
                    float v1 = acc[i][j][r] + bv[j];
                    float v2 = acc[i][j + 2][r] + bv[j + 2];
                    int n1 = wc * 64 + j * 16 + lr;
                    Ct[mrow * 136 + n1]      = f2bf((v1 * cs.x - v2 * cs.y) * qs);
                    Ct[mrow * 136 + n1 + 32] = f2bf((v2 * cs.x + v1 * cs.y) * qs);
                }
            }
        __syncthreads();
#pragma unroll
        for (int p = 0; p < 4; ++p) {
            int idx = p * 512 + tid;              // 128 rows x 16 chunks of 8 u16
            int mrow = idx >> 4, c = idx & 15;
            s16x8 vdat = *(const s16x8*)&Ct[mrow * 136 + c * 8];
            int h = h0 + (c >> 3), dd = (c & 7) << 3;
            *(s16x8*)(dst + ((size_t)(b * NH + h) * T_SEQ + tbase + mrow) * HD + dd) = vdat;
        }
    }
}

// ---------------- k2: flash attention (64-row Q tile, XOR-swizzled LDS) ----
// grid (32, 32), 256 threads / 4 waves / 1 strip each. qt = q-tile of 64
// rows; wave w owns rows [qt*64+16w, +16). 1024 blocks = whole grid
// co-resident at 4 blocks/CU (LDS 32KB). Mask only on kt==qt.
// K/V LDS: [64][64] linear, 8-slot XOR swizzle LDS[row][s]=G[row][s^(row&7)]
// (reg-staged writes swizzle the LDS addr). ak slot=(ks*4+quad)^(lr&7);
// av slot=(2tc+(quad>>1))^(lr&7), +4 u16 if quad odd. All bank-uniform.
// S^T: elem (k'=k0+tc*16+quad*4+r, q=rbase+lr). PV: 16x16x16, P in regs.
// Double-buffered K/V, one barrier per k-tile. T5 setprio around MFMAs.
__global__ __launch_bounds__(256, 4) void flash_k(const u16* __restrict__ qb, const u16* __restrict__ kb,
                                                  const u16* __restrict__ vt, u16* __restrict__ yab) {
    __shared__ u16 Ks[2][64 * 64];
    __shared__ u16 Vs[2][64 * 64];
    int tid = threadIdx.x;
    int bx = blockIdx.x, by = blockIdx.y;
    int qt = (by < 16) ? (31 - bx) : bx;      // complementary pairing for balance
    int bh = by;
    int w = tid >> 6, lane = tid & 63, lr = lane & 15, quad = lane >> 4;
    int q0 = qt * 64;
    const u16* qh = qb + (size_t)bh * T_SEQ * HD;
    const u16* kh = kb + (size_t)bh * T_SEQ * HD;
    const u16* vh = vt + (size_t)bh * HD * T_SEQ;

    int rbase = q0 + w * 16;                  // this wave's strip

    s16x8 aq[2];                              // B-frag of Q (n=q-row=lr, k=d)
#pragma unroll
    for (int ks = 0; ks < 2; ++ks)
        aq[ks] = *(const s16x8*)(qh + (size_t)(rbase + lr) * HD + ks * 32 + quad * 8);

    int srow = tid >> 3, sc8 = (tid & 7) << 3;       // staging: rows srow, srow+32
    int swsl = (((tid & 7) ^ (srow & 7)) << 3);      // swizzled LDS write col (u16)
    int lrx8 = (lr & 7) << 3;                        // fragment-read XOR key (u16 units)

    float m_i = -1e30f;
    f32x4 l4 = {0.f, 0.f, 0.f, 0.f};          // per-lane l partials
    f32x4 oacc[4] = {};                       // O^T: elem (d=dn*16+quad*4+r, q=lr)

    int ktmax = qt;
    {   // prologue: stage tile 0 into buffer 0 (2 K-rows + 2 V-rows / thread)
        s16x8 ka = *(const s16x8*)(kh + (size_t)srow * HD + sc8);
        s16x8 kb2 = *(const s16x8*)(kh + (size_t)(srow + 32) * HD + sc8);
        s16x8 va = *(const s16x8*)(vh + (size_t)srow * T_SEQ + sc8);
        s16x8 vb = *(const s16x8*)(vh + (size_t)(srow + 32) * T_SEQ + sc8);
        *(s16x8*)&Ks[0][srow * 64 + swsl] = ka;
        *(s16x8*)&Ks[0][(srow + 32) * 64 + swsl] = kb2;
        *(s16x8*)&Vs[0][srow * 64 + swsl] = va;
        *(s16x8*)&Vs[0][(srow + 32) * 64 + swsl] = vb;
    }
    __syncthreads();

    for (int kt = 0; kt <= ktmax; ++kt) {
        int cur = kt & 1;
        int k0 = kt * 64;
        bool pf = kt < ktmax;
        s16x8 kr0, kr1, vr0, vr1;             // next-tile prefetch registers
        if (pf) {
            int kn = k0 + 64;
            kr0 = *(const s16x8*)(kh + (size_t)(kn + srow) * HD + sc8);
            kr1 = *(const s16x8*)(kh + (size_t)(kn + srow + 32) * HD + sc8);
            vr0 = *(const s16x8*)(vh + (size_t)srow * T_SEQ + kn + sc8);
            vr1 = *(const s16x8*)(vh + (size_t)(srow + 32) * T_SEQ + kn + sc8);
        }
        const u16* Kc = Ks[cur];
        const u16* Vc = Vs[cur];

        // fragments (all strips active every tile in the 64-row form)
        s16x8 ak[2][4];                       // K frag (m=k-row=lr, k=d)
#pragma unroll
        for (int ks = 0; ks < 2; ++ks)
#pragma unroll
            for (int tc = 0; tc < 4; ++tc)
                ak[ks][tc] = *(const s16x8*)&Kc[(tc * 16 + lr) * 64 + (((ks * 4 + quad) << 3) ^ lrx8)];
        s16x4 av[4][4];                       // V^T frag (m=d=dn*16+lr, k=tc*16+quad*4+j)
#pragma unroll
        for (int dn = 0; dn < 4; ++dn) {
            const u16* vrow = &Vc[(dn * 16 + lr) * 64 + ((quad & 1) << 2)];
#pragma unroll
            for (int tc = 0; tc < 4; ++tc)
                av[dn][tc] = *(const s16x4*)(vrow + ((((tc << 1) + (quad >> 1)) << 3) ^ lrx8));
        }
        f32x4 sacc[4] = {};
        __builtin_amdgcn_s_setprio(1);        // T5: favor MFMA wave
#pragma unroll
        for (int ks = 0; ks < 2; ++ks)
#pragma unroll
            for (int tc = 0; tc < 4; ++tc) sacc[tc] = MFMA16(ak[ks][tc], aq[ks], sacc[tc]);
        __builtin_amdgcn_s_setprio(0);
        if (kt == ktmax) {                    // diagonal tile: causal mask
#pragma unroll
            for (int tc = 0; tc < 4; ++tc)
#pragma unroll
                for (int r = 0; r < 4; ++r)
                    if (k0 + tc * 16 + quad * 4 + r > rbase + lr) sacc[tc][r] = -1e30f;
        }
        // per-lane local max; __all == row-max guard
        f32x4 mv = sacc[0];
#pragma unroll
        for (int tc = 1; tc < 4; ++tc)
#pragma unroll
            for (int r = 0; r < 4; ++r) mv[r] = fmaxf(mv[r], sacc[tc][r]);
        float loc = fmaxf(fmaxf(mv[0], mv[1]), fmaxf(mv[2], mv[3]));
        bool need = !__all(loc <= m_i + 8.0f);   // defer-max (T13, THR=8)
        float alpha = 1.0f;
        if (need) {                            // rare: full cross-lane max
            float mx = fmaxf(loc, __shfl_xor(loc, 16, 64));
            mx = fmaxf(mx, __shfl_xor(mx, 32, 64));
            float mn = fmaxf(m_i, mx);
            alpha = __builtin_exp2f(m_i - mn);
            m_i = mn;
#pragma unroll
            for (int r = 0; r < 4; ++r) l4[r] *= alpha;
        }
        float mnow = m_i;
#pragma unroll
        for (int tc = 0; tc < 4; ++tc)
#pragma unroll
            for (int r = 0; r < 4; ++r) {
                float p = __builtin_exp2f(sacc[tc][r] - mnow);
                sacc[tc][r] = p;
                l4[r] += p;                    // per-lane partial; folded at end
            }
        // P in registers: pack4cvt(sacc[tc]) IS the 16x16x16 B-frag
        s16x4 pa[4];
#pragma unroll
        for (int tc = 0; tc < 4; ++tc) pa[tc] = pack4cvt_s(sacc[tc]);
        if (need) {
#pragma unroll
            for (int dn = 0; dn < 4; ++dn)
#pragma unroll
                for (int r = 0; r < 4; ++r) oacc[dn][r] *= alpha;
        }
        __builtin_amdgcn_s_setprio(1);        // T5: favor MFMA wave
#pragma unroll
        for (int dn = 0; dn < 4; ++dn)
#pragma unroll
            for (int tc = 0; tc < 4; ++tc)
                oacc[dn] = MFMA16K16(av[dn][tc], pa[tc], oacc[dn]);
        __builtin_amdgcn_s_setprio(0);

        if (pf) {                              // write prefetched tile to other buffer
            int nx = cur ^ 1;
            *(s16x8*)&Ks[nx][srow * 64 + swsl] = kr0;
            *(s16x8*)&Ks[nx][(srow + 32) * 64 + swsl] = kr1;
            *(s16x8*)&Vs[nx][srow * 64 + swsl] = vr0;
            *(s16x8*)&Vs[nx][(srow + 32) * 64 + swsl] = vr1;
        }
        __syncthreads();                       // single barrier per k-tile
    }
    // fold l partials: 4 per-lane + the 4 lanes of each row (xor 16, 32)
    float rs = (l4[0] + l4[1]) + (l4[2] + l4[3]);
    rs += __shfl_xor(rs, 16, 64);
    rs += __shfl_xor(rs, 32, 64);
    int b = bh >> 4, hh = bh & 15;
    {
        float inv = 1.f / rs;
        int t = rbase + lr;
        size_t base = ((size_t)b * T_SEQ + t) * C_EMB + hh * HD;
#pragma unroll
        for (int dn = 0; dn < 4; ++dn) {
            f32x4 vv;
#pragma unroll
            for (int r = 0; r < 4; ++r) vv[r] = oacc[dn][r] * inv;
            *(u16x4*)(yab + base + dn * 16 + quad * 4) = pack4(vv);
        }
    }
}

// ---------------- k3: output projection (64x64 tiles, BK=64, dbuf) ---------
// grid (16, 64): n0 = bx*64, m0 = by*64. 256 thr / 4 waves; wave (wr,wc)
// owns 32x32 (acc[2][2]). LDS 32KB -> 4 blocks/CU x 4 waves = 16 waves/CU.
// 16 K-iters: per iter 4 gload16/thread, 8 b128 frag reads, 8 MFMA/wave,
// vmcnt(4) + 2 barriers. 8-slot XOR swizzle (qkv-verified).
__global__ __launch_bounds__(256) void proj_k(const u16* __restrict__ ya, const u16* __restrict__ Wpb,
                                              const float* __restrict__ bias, float* __restrict__ out) {
    __shared__ u16 As[2][4096];               // [buf][64][64] linear (content swizzled)
    __shared__ u16 Bs[2][4096];
    int tid = threadIdx.x;
    int n0 = blockIdx.x * 64, m0 = blockIdx.y * 64;
    int w = tid >> 6, lane = tid & 63, lr = lane & 15, quad = lane >> 4;
    int wr = w >> 1, wc = w & 1;
    f32x4 acc[2][2] = {};
    int srow = tid >> 3;                                  // staging row 0..31 (+32 second chunk)
    int swc8 = (((tid & 7) ^ (srow & 7)) << 3);           // pre-swizzled src col (u16)
    int soff = tid * 8;                                   // linear LDS u16 offset
    int lrx = lr & 7;                                     // fragment-read XOR key

#define PRJ_STAGE(bufi, kc) do {                                                     \
        gload16(ya  + (size_t)(m0 + srow) * C_EMB + (kc) + swc8,      &As[bufi][soff]);        \
        gload16(ya  + (size_t)(m0 + 32 + srow) * C_EMB + (kc) + swc8, &As[bufi][2048 + soff]); \
        gload16(Wpb + (size_t)(n0 + srow) * C_EMB + (kc) + swc8,      &Bs[bufi][soff]);        \
        gload16(Wpb + (size_t)(n0 + 32 + srow) * C_EMB + (kc) + swc8, &Bs[bufi][2048 + soff]); \
    } while (0)

    PRJ_STAGE(0, 0);
#pragma unroll 2
    for (int kt = 0; kt < 16; ++kt) {
        int cur = kt & 1;
        if (kt < 15) {
            PRJ_STAGE(cur ^ 1, (kt + 1) * 64);
            asm volatile("s_waitcnt vmcnt(4)" ::: "memory");
        } else {
            asm volatile("s_waitcnt vmcnt(0)" ::: "memory");
        }
        __builtin_amdgcn_s_barrier();
        asm volatile("" ::: "memory");
#pragma unroll
        for (int ks = 0; ks < 64; ks += 32) {
            int slot = (ks >> 3) + quad;                   // 0..7
            int rc8 = ((slot ^ lrx) << 3);                 // swizzled read col (u16)
            s16x8 af[2], bf[2];
#pragma unroll
            for (int i = 0; i < 2; ++i)
                af[i] = *(const s16x8*)&As[cur][(wr * 32 + i * 16 + lr) * 64 + rc8];
#pragma unroll
            for (int j = 0; j < 2; ++j)
                bf[j] = *(const s16x8*)&Bs[cur][(wc * 32 + j * 16 + lr) * 64 + rc8];
#pragma unroll
            for (int i = 0; i < 2; ++i)
#pragma unroll
                for (int j = 0; j < 2; ++j) acc[i][j] = MFMA16(af[i], bf[j], acc[i][j]);
        }
        asm volatile("" ::: "memory");
        __builtin_amdgcn_s_barrier();
    }
#undef PRJ_STAGE

    float bv[2];
#pragma unroll
    for (int j = 0; j < 2; ++j) bv[j] = bias[n0 + wc * 32 + j * 16 + lr];
#pragma unroll
    for (int i = 0; i < 2; ++i)
#pragma unroll
        for (int r = 0; r < 4; ++r) {
            int m = m0 + wr * 32 + i * 16 + quad * 4 + r;
#pragma unroll
            for (int j = 0; j < 2; ++j)
                out[(size_t)m * C_EMB + n0 + wc * 32 + j * 16 + lr] = acc[i][j][r] + bv[j];
        }
}

extern "C" void kernel_launch(void* const* d_in, const int* in_sizes, int n_in,
                              void* d_out, int out_size, void* d_ws, size_t ws_size,
                              hipStream_t stream) {
    // Inputs resolved BY ELEMENT COUNT (unique): x 4194304, W_attn 3145728,
    // b_attn 3072, W_proj 1048576, b_proj 1024. All fp32.
    const float *x = nullptr, *Wa = nullptr, *ba = nullptr, *Wp = nullptr, *bp = nullptr;
    for (int i = 0; i < n_in; ++i) {
        switch (in_sizes[i]) {
            case 4194304: x  = (const float*)d_in[i]; break;
            case 3145728: Wa = (const float*)d_in[i]; break;
            case 3072:    ba = (const float*)d_in[i]; break;
            case 1048576: Wp = (const float*)d_in[i]; break;
            case 1024:    bp = (const float*)d_in[i]; break;
            default: break;
        }
    }
    float* out = (float*)d_out;

    char* ws = (char*)d_ws;
    u16* qb     = (u16*)(ws);                    //  0.. 8 MiB  bf16 [B,H,T,D] (q*0.125*log2e)
    u16* kb     = (u16*)(ws + 8388608);          //  8..16 MiB  bf16 [B,H,T,D]
    u16* vt     = (u16*)(ws + 16777216);         // 16..24 MiB  bf16 [B,H,D,T]
    u16* yab    = (u16*)(ws + 25165824);         // 24..32 MiB  bf16 [B,T,C]
    float2* tab = (float2*)(ws + 33554432);      // 32..32.5 MiB
    u16* xb     = (u16*)(ws + 35651584);         // 34..42 MiB  bf16 [4096,1024]
    u16* Wab    = (u16*)(ws + 44040192);         // 42..48 MiB  bf16 [3072,1024]
    u16* Wpb    = (u16*)(ws + 50331648);         // 48..50 MiB  bf16 [1024,1024]

    prep_k<<<4352, 256, 0, stream>>>(x, Wa, Wp, xb, Wab, Wpb, tab);
    qkv_rope_k<<<dim3(24, 32), 512, 0, stream>>>(xb, Wab, ba, tab, qb, kb, vt);
    flash_k<<<dim3(32, 32), 256, 0, stream>>>(qb, kb, vt, yab);
    proj_k<<<dim3(16, 64), 256, 0, stream>>>(yab, Wpb, bp, out);
}

// Round 20
// 181.249 us; speedup vs baseline: 1.0425x; 1.0042x over previous
//
#include <hip/hip_runtime.h>

// B=2, T=2048, C=1024, H=16, D=64. Inputs fp32, OUTPUT fp32.
// Round 32 (post-mortem R31: qkv 512-thr widening paid, 182.0 best; flash
// sole top-5 leader at 52.6, latency-floor-bound. Last kernel at low wave
// count is proj -> third application of the proven wave-widening transform):
//  - proj_k: 512 threads / 8 waves (4x2 wave grid; wave owns 16x32, acc[2]),
//    same 64x64 tile BK=64 dbuf. Staging = exactly 1 gload/thread per
//    matrix; counted vmcnt(2). Grid (16,64) = 4 blocks/CU x 8 waves =
//    32 waves/CU (full capacity; LDS 32KB x4 = 128KB, VGPR ~40).
//  - prep_k / qkv_rope_k (512-thr R31) / flash_k (52.0-best R28) unchanged.
// MFMA 16x16x32_bf16 layouts (HW-verified): A: m=lane&15,k=quad*8+j;
// B: k=quad*8+j,n=lane&15; C/D: col=lane&15,row=quad*4+reg.
// MFMA 16x16x16_bf16 (HW-verified R17): A: m=lane&15,k=quad*4+j;
// B: k=quad*4+j,n=lane&15; C/D: col=lane&15,row=quad*4+reg.

typedef unsigned short u16;
typedef u16 u16x4 __attribute__((ext_vector_type(4)));
typedef u16 u16x8 __attribute__((ext_vector_type(8)));
typedef short s16x4 __attribute__((ext_vector_type(4)));
typedef short s16x8 __attribute__((ext_vector_type(8)));
typedef float f32x4 __attribute__((ext_vector_type(4)));

#define T_SEQ 2048
#define C_EMB 1024
#define NH 16
#define HD 64

#define MFMA16(a, b, c) __builtin_amdgcn_mfma_f32_16x16x32_bf16(a, b, c, 0, 0, 0)

__device__ __forceinline__ f32x4 MFMA16K16(s16x4 a, s16x4 b, f32x4 c) {
#if __has_builtin(__builtin_amdgcn_mfma_f32_16x16x16bf16_1k)
    return __builtin_amdgcn_mfma_f32_16x16x16bf16_1k(a, b, c, 0, 0, 0);
#else
    asm("v_mfma_f32_16x16x16_bf16 %0, %1, %2, %0" : "+v"(c) : "v"(a), "v"(b));
    return c;
#endif
}

__device__ __forceinline__ u16 f2bf(float f) {
    union { float f; unsigned int i; } x; x.f = f;
    unsigned int r = x.i + 0x7fffu + ((x.i >> 16) & 1u);
    return (u16)(r >> 16);
}
__device__ __forceinline__ u16x4 pack4(f32x4 v) {
    u16x4 o;
#pragma unroll
    for (int j = 0; j < 4; ++j) o[j] = f2bf(v[j]);
    return o;
}
// hot-loop pack: HW packed convert (RNE), 2 instr per 4 values -> s16x4 frag
__device__ __forceinline__ s16x4 pack4cvt_s(f32x4 v) {
    union { s16x4 h; unsigned int w[2]; } u;
    asm("v_cvt_pk_bf16_f32 %0, %1, %2" : "=v"(u.w[0]) : "v"(v[0]), "v"(v[1]));
    asm("v_cvt_pk_bf16_f32 %0, %1, %2" : "=v"(u.w[1]) : "v"(v[2]), "v"(v[3]));
    return u.h;
}
// async global->LDS, 16B per lane (dest must be wave-uniform base + lane*16)
__device__ __forceinline__ void gload16(const void* g, void* l) {
    __builtin_amdgcn_global_load_lds(
        (const __attribute__((address_space(1))) unsigned int*)g,
        (__attribute__((address_space(3))) unsigned int*)l, 16, 0, 0);
}

// ---------------- k0: merged prep (3x fp32->bf16 conv + rope tables) -------
// grid 4352: [0,2048) conv x; [2048,3584) conv Wa; [3584,4096) conv Wp;
// [4096,4352) rope tables. All sections exact-sized (no bounds checks).
__global__ __launch_bounds__(256) void prep_k(const float* __restrict__ x, const float* __restrict__ Wa,
                                              const float* __restrict__ Wp,
                                              u16* __restrict__ xb, u16* __restrict__ Wab,
                                              u16* __restrict__ Wpb, float2* __restrict__ tab) {
    int bid = blockIdx.x, tid = threadIdx.x;
    if (bid < 4096) {
        const float* src;
        u16* dst;
        int i;
        if (bid < 2048)      { src = x;  dst = xb;  i = bid * 256 + tid; }
        else if (bid < 3584) { src = Wa; dst = Wab; i = (bid - 2048) * 256 + tid; }
        else                 { src = Wp; dst = Wpb; i = (bid - 3584) * 256 + tid; }
        f32x4 a = ((const f32x4*)src)[i * 2];
        f32x4 b = ((const f32x4*)src)[i * 2 + 1];
        u16x8 o;
#pragma unroll
        for (int j = 0; j < 4; ++j) o[j] = f2bf(a[j]);
#pragma unroll
        for (int j = 0; j < 4; ++j) o[4 + j] = f2bf(b[j]);
        ((u16x8*)dst)[i] = o;
    } else {
        int idx = (bid - 4096) * 256 + tid;   // 65536 = T*32
        int t = idx >> 5, j = idx & 31;
        float inv = __builtin_exp2f(-0.41524101186092f * (float)j);  // 10000^(-j/32)
        float s_, c_;
        sincosf((float)t * inv, &s_, &c_);
        tab[idx] = make_float2(c_, s_);
    }
}

// ---------------- k1: QKV GEMM + RoPE (512 thr, BK=32, 3-deep pipeline) ----
// grid (24, 32): n0 = bx*128 (0..3071), m0 = by*128 (0..4095).
// 8 waves (4x2): wave (wr,wc) owns rows wr*32..+32, cols wc*64..+64
// (acc[2][4]). Staging: 2 gloads/thread = full 16KB A+B tile pair.
// 24 waves/CU (3 blocks x 8). 4-slot XOR swizzle (R18-verified).
__global__ __launch_bounds__(512) void qkv_rope_k(const u16* __restrict__ xb, const u16* __restrict__ Wab,
                                                  const float* __restrict__ bias,
                                                  const float2* __restrict__ tab,
                                                  u16* __restrict__ qb, u16* __restrict__ kb,
                                                  u16* __restrict__ vt) {
    __shared__ u16 smem[24576];               // As[3][4096] | Bs[3][4096] = 48KB; Ct[17408] unions
    u16* As = smem;                           // [buf][128][32] linear (content swizzled)
    u16* Bs = smem + 12288;
    int tid = threadIdx.x;
    int n0 = blockIdx.x * 128, m0 = blockIdx.y * 128;
    int w = tid >> 6, lane = tid & 63, lr = lane & 15, quad = lane >> 4;
    int wr = w >> 1, wc = w & 1;              // 4x2 wave grid
    f32x4 acc[2][4] = {};
    int srow = tid >> 2;                                  // staging row 0..127
    int swc8 = (((tid & 3) ^ (srow & 3)) << 3);           // pre-swizzled src col (u16)
    int soff = tid * 8;                                   // linear LDS u16 offset
    int rc8 = ((quad ^ (lr & 3)) << 3);                   // swizzled fragment-read col

#define QKV_STAGE(bufi, kc) do {                                              \
        int _b = (bufi) * 4096;                                               \
        gload16(xb  + (size_t)(m0 + srow) * C_EMB + (kc) + swc8, &As[_b + soff]); \
        gload16(Wab + (size_t)(n0 + srow) * C_EMB + (kc) + swc8, &Bs[_b + soff]); \
    } while (0)

    QKV_STAGE(0, 0);
    QKV_STAGE(1, 32);
    int cur = 0;
    for (int kt = 0; kt < 32; ++kt) {
        if (kt < 30) {
            int nb = cur + 2; if (nb >= 3) nb -= 3;
            QKV_STAGE(nb, (kt + 2) * 32);
            asm volatile("s_waitcnt vmcnt(4)" ::: "memory");   // tile-kt loads done
        } else if (kt == 30) {
            asm volatile("s_waitcnt vmcnt(2)" ::: "memory");
        } else {
            asm volatile("s_waitcnt vmcnt(0)" ::: "memory");
        }
        __builtin_amdgcn_s_barrier();
        asm volatile("" ::: "memory");
        int cb = cur * 4096;
        s16x8 af[2], bf[4];
#pragma unroll
        for (int i = 0; i < 2; ++i)
            af[i] = *(const s16x8*)&As[cb + (wr * 32 + i * 16 + lr) * 32 + rc8];
#pragma unroll
        for (int j = 0; j < 4; ++j)
            bf[j] = *(const s16x8*)&Bs[cb + (wc * 64 + j * 16 + lr) * 32 + rc8];
#pragma unroll
        for (int i = 0; i < 2; ++i)
#pragma unroll
            for (int j = 0; j < 4; ++j) acc[i][j] = MFMA16(af[i], bf[j], acc[i][j]);
        asm volatile("" ::: "memory");
        __builtin_amdgcn_s_barrier();
        cur = cur + 1; if (cur >= 3) cur -= 3;
    }
#undef QKV_STAGE

    int sec = n0 >> 10;                       // 0=q 1=k 2=v (blocks never straddle)
    float bv[4];
#pragma unroll
    for (int j = 0; j < 4; ++j) bv[j] = bias[n0 + wc * 64 + j * 16 + lr];

    int h0 = (n0 & 1023) >> 6;
    int b = m0 >> 11, tbase = m0 & 2047;
    if (sec == 2) {
        // C tile (+bias) -> LDS [d][m] (136-padded) -> coalesced 16B
        // transposed stores to vt[((b*16+h)*64+d)*2048 + t].
        u16* Ct = smem;                        // 128 x 136 u16 = 34816 B
        __syncthreads();                       // frag reads done before overwrite
#pragma unroll
        for (int i = 0; i < 2; ++i)
#pragma unroll
            for (int j = 0; j < 4; ++j) {
                f32x4 vv;
#pragma unroll
                for (int r = 0; r < 4; ++r) vv[r] = acc[i][j][r] + bv[j];
                int d = wc * 64 + j * 16 + lr;
                int m4 = wr * 32 + i * 16 + quad * 4;
                *(u16x4*)&Ct[d * 136 + m4] = pack4(vv);
            }
        __syncthreads();
        size_t hb = (size_t)(b * NH);
#pragma unroll
        for (int p = 0; p < 4; ++p) {
            int idx = p * 512 + tid;
            int d = idx >> 4, mc = (idx & 15) << 3;
            s16x8 vdat = *(const s16x8*)&Ct[d * 136 + mc];
            int h = h0 + (d >> 6), dd = d & 63;
            *(s16x8*)(vt + ((hb + h) * HD + dd) * T_SEQ + tbase + mc) = vdat;
        }
    } else {
        // q/k: RoPE in-register, stage [m][n] in LDS, coalesced b128 stores.
        u16* dst = (sec == 0) ? qb : kb;
        // fold 1/sqrt(D) AND log2(e) into q so flash softmax is native base-2:
        float qs = (sec == 0) ? 0.18033688011112043f : 1.0f;
        u16* Ct = smem;                        // 128 x 136 u16
        __syncthreads();                       // all frag reads done before overwrite
#pragma unroll
        for (int i = 0; i < 2; ++i)
#pragma unroll
            for (int r = 0; r < 4; ++r) {
                int mrow = wr * 32 + i * 16 + quad * 4 + r;
                int t = (m0 + mrow) & 2047;
#pragma unroll
                for (int j = 0; j < 2; ++j) {
                    int d1 = j * 16 + lr;                 // 0..31; partner +32 in tile j+2
                    float2 cs = tab[t * 32 + d1];
                    float v1 = acc[i][j][r] + bv[j];
                    float v2 = acc[i][j + 2][r] + bv[j + 2];
                    int n1 = wc * 64 + j * 16 + lr;
                    Ct[mrow * 136 + n1]      = f2bf((v1 * cs.x - v2 * cs.y) * qs);
                    Ct[mrow * 136 + n1 + 32] = f2bf((v2 * cs.x + v1 * cs.y) * qs);
                }
            }
        __syncthreads();
#pragma unroll
        for (int p = 0; p < 4; ++p) {
            int idx = p * 512 + tid;              // 128 rows x 16 chunks of 8 u16
            int mrow = idx >> 4, c = idx & 15;
            s16x8 vdat = *(const s16x8*)&Ct[mrow * 136 + c * 8];
            int h = h0 + (c >> 3), dd = (c & 7) << 3;
            *(s16x8*)(dst + ((size_t)(b * NH + h) * T_SEQ + tbase + mrow) * HD + dd) = vdat;
        }
    }
}

// ---------------- k2: flash attention (64-row Q tile, XOR-swizzled LDS) ----
// grid (32, 32), 256 threads / 4 waves / 1 strip each. qt = q-tile of 64
// rows; wave w owns rows [qt*64+16w, +16). 1024 blocks = whole grid
// co-resident at 4 blocks/CU (LDS 32KB). Mask only on kt==qt.
// K/V LDS: [64][64] linear, 8-slot XOR swizzle LDS[row][s]=G[row][s^(row&7)]
// (reg-staged writes swizzle the LDS addr). ak slot=(ks*4+quad)^(lr&7);
// av slot=(2tc+(quad>>1))^(lr&7), +4 u16 if quad odd. All bank-uniform.
// S^T: elem (k'=k0+tc*16+quad*4+r, q=rbase+lr). PV: 16x16x16, P in regs.
// Double-buffered K/V, one barrier per k-tile. T5 setprio around MFMAs.
__global__ __launch_bounds__(256, 4) void flash_k(const u16* __restrict__ qb, const u16* __restrict__ kb,
                                                  const u16* __restrict__ vt, u16* __restrict__ yab) {
    __shared__ u16 Ks[2][64 * 64];
    __shared__ u16 Vs[2][64 * 64];
    int tid = threadIdx.x;
    int bx = blockIdx.x, by = blockIdx.y;
    int qt = (by < 16) ? (31 - bx) : bx;      // complementary pairing for balance
    int bh = by;
    int w = tid >> 6, lane = tid & 63, lr = lane & 15, quad = lane >> 4;
    int q0 = qt * 64;
    const u16* qh = qb + (size_t)bh * T_SEQ * HD;
    const u16* kh = kb + (size_t)bh * T_SEQ * HD;
    const u16* vh = vt + (size_t)bh * HD * T_SEQ;

    int rbase = q0 + w * 16;                  // this wave's strip

    s16x8 aq[2];                              // B-frag of Q (n=q-row=lr, k=d)
#pragma unroll
    for (int ks = 0; ks < 2; ++ks)
        aq[ks] = *(const s16x8*)(qh + (size_t)(rbase + lr) * HD + ks * 32 + quad * 8);

    int srow = tid >> 3, sc8 = (tid & 7) << 3;       // staging: rows srow, srow+32
    int swsl = (((tid & 7) ^ (srow & 7)) << 3);      // swizzled LDS write col (u16)
    int lrx8 = (lr & 7) << 3;                        // fragment-read XOR key (u16 units)

    float m_i = -1e30f;
    f32x4 l4 = {0.f, 0.f, 0.f, 0.f};          // per-lane l partials
    f32x4 oacc[4] = {};                       // O^T: elem (d=dn*16+quad*4+r, q=lr)

    int ktmax = qt;
    {   // prologue: stage tile 0 into buffer 0 (2 K-rows + 2 V-rows / thread)
        s16x8 ka = *(const s16x8*)(kh + (size_t)srow * HD + sc8);
        s16x8 kb2 = *(const s16x8*)(kh + (size_t)(srow + 32) * HD + sc8);
        s16x8 va = *(const s16x8*)(vh + (size_t)srow * T_SEQ + sc8);
        s16x8 vb = *(const s16x8*)(vh + (size_t)(srow + 32) * T_SEQ + sc8);
        *(s16x8*)&Ks[0][srow * 64 + swsl] = ka;
        *(s16x8*)&Ks[0][(srow + 32) * 64 + swsl] = kb2;
        *(s16x8*)&Vs[0][srow * 64 + swsl] = va;
        *(s16x8*)&Vs[0][(srow + 32) * 64 + swsl] = vb;
    }
    __syncthreads();

    for (int kt = 0; kt <= ktmax; ++kt) {
        int cur = kt & 1;
        int k0 = kt * 64;
        bool pf = kt < ktmax;
        s16x8 kr0, kr1, vr0, vr1;             // next-tile prefetch registers
        if (pf) {
            int kn = k0 + 64;
            kr0 = *(const s16x8*)(kh + (size_t)(kn + srow) * HD + sc8);
            kr1 = *(const s16x8*)(kh + (size_t)(kn + srow + 32) * HD + sc8);
            vr0 = *(const s16x8*)(vh + (size_t)srow * T_SEQ + kn + sc8);
            vr1 = *(const s16x8*)(vh + (size_t)(srow + 32) * T_SEQ + kn + sc8);
        }
        const u16* Kc = Ks[cur];
        const u16* Vc = Vs[cur];

        // fragments (all strips active every tile in the 64-row form)
        s16x8 ak[2][4];                       // K frag (m=k-row=lr, k=d)
#pragma unroll
        for (int ks = 0; ks < 2; ++ks)
#pragma unroll
            for (int tc = 0; tc < 4; ++tc)
                ak[ks][tc] = *(const s16x8*)&Kc[(tc * 16 + lr) * 64 + (((ks * 4 + quad) << 3) ^ lrx8)];
        s16x4 av[4][4];                       // V^T frag (m=d=dn*16+lr, k=tc*16+quad*4+j)
#pragma unroll
        for (int dn = 0; dn < 4; ++dn) {
            const u16* vrow = &Vc[(dn * 16 + lr) * 64 + ((quad & 1) << 2)];
#pragma unroll
            for (int tc = 0; tc < 4; ++tc)
                av[dn][tc] = *(const s16x4*)(vrow + ((((tc << 1) + (quad >> 1)) << 3) ^ lrx8));
        }
        f32x4 sacc[4] = {};
        __builtin_amdgcn_s_setprio(1);        // T5: favor MFMA wave
#pragma unroll
        for (int ks = 0; ks < 2; ++ks)
#pragma unroll
            for (int tc = 0; tc < 4; ++tc) sacc[tc] = MFMA16(ak[ks][tc], aq[ks], sacc[tc]);
        __builtin_amdgcn_s_setprio(0);
        if (kt == ktmax) {                    // diagonal tile: causal mask
#pragma unroll
            for (int tc = 0; tc < 4; ++tc)
#pragma unroll
                for (int r = 0; r < 4; ++r)
                    if (k0 + tc * 16 + quad * 4 + r > rbase + lr) sacc[tc][r] = -1e30f;
        }
        // per-lane local max; __all == row-max guard
        f32x4 mv = sacc[0];
#pragma unroll
        for (int tc = 1; tc < 4; ++tc)
#pragma unroll
            for (int r = 0; r < 4; ++r) mv[r] = fmaxf(mv[r], sacc[tc][r]);
        float loc = fmaxf(fmaxf(mv[0], mv[1]), fmaxf(mv[2], mv[3]));
        bool need = !__all(loc <= m_i + 8.0f);   // defer-max (T13, THR=8)
        float alpha = 1.0f;
        if (need) {                            // rare: full cross-lane max
            float mx = fmaxf(loc, __shfl_xor(loc, 16, 64));
            mx = fmaxf(mx, __shfl_xor(mx, 32, 64));
            float mn = fmaxf(m_i, mx);
            alpha = __builtin_exp2f(m_i - mn);
            m_i = mn;
#pragma unroll
            for (int r = 0; r < 4; ++r) l4[r] *= alpha;
        }
        float mnow = m_i;
#pragma unroll
        for (int tc = 0; tc < 4; ++tc)
#pragma unroll
            for (int r = 0; r < 4; ++r) {
                float p = __builtin_exp2f(sacc[tc][r] - mnow);
                sacc[tc][r] = p;
                l4[r] += p;                    // per-lane partial; folded at end
            }
        // P in registers: pack4cvt(sacc[tc]) IS the 16x16x16 B-frag
        s16x4 pa[4];
#pragma unroll
        for (int tc = 0; tc < 4; ++tc) pa[tc] = pack4cvt_s(sacc[tc]);
        if (need) {
#pragma unroll
            for (int dn = 0; dn < 4; ++dn)
#pragma unroll
                for (int r = 0; r < 4; ++r) oacc[dn][r] *= alpha;
        }
        __builtin_amdgcn_s_setprio(1);        // T5: favor MFMA wave
#pragma unroll
        for (int dn = 0; dn < 4; ++dn)
#pragma unroll
            for (int tc = 0; tc < 4; ++tc)
                oacc[dn] = MFMA16K16(av[dn][tc], pa[tc], oacc[dn]);
        __builtin_amdgcn_s_setprio(0);

        if (pf) {                              // write prefetched tile to other buffer
            int nx = cur ^ 1;
            *(s16x8*)&Ks[nx][srow * 64 + swsl] = kr0;
            *(s16x8*)&Ks[nx][(srow + 32) * 64 + swsl] = kr1;
            *(s16x8*)&Vs[nx][srow * 64 + swsl] = vr0;
            *(s16x8*)&Vs[nx][(srow + 32) * 64 + swsl] = vr1;
        }
        __syncthreads();                       // single barrier per k-tile
    }
    // fold l partials: 4 per-lane + the 4 lanes of each row (xor 16, 32)
    float rs = (l4[0] + l4[1]) + (l4[2] + l4[3]);
    rs += __shfl_xor(rs, 16, 64);
    rs += __shfl_xor(rs, 32, 64);
    int b = bh >> 4, hh = bh & 15;
    {
        float inv = 1.f / rs;
        int t = rbase + lr;
        size_t base = ((size_t)b * T_SEQ + t) * C_EMB + hh * HD;
#pragma unroll
        for (int dn = 0; dn < 4; ++dn) {
            f32x4 vv;
#pragma unroll
            for (int r = 0; r < 4; ++r) vv[r] = oacc[dn][r] * inv;
            *(u16x4*)(yab + base + dn * 16 + quad * 4) = pack4(vv);
        }
    }
}

// ---------------- k3: output projection (512 thr, 64x64, BK=64, dbuf) ------
// grid (16, 64): n0 = bx*64, m0 = by*64. 512 thr / 8 waves (4x2): wave
// (wr,wc) owns rows wr*16..+16, cols wc*32..+32 (acc[2]). LDS 32KB ->
// 4 blocks/CU x 8 waves = 32 waves/CU (full capacity). 16 K-iters: per iter
// 2 gload16/thread (one per matrix), vmcnt(2), 2 barriers, 4 MFMA/wave.
// 8-slot XOR swizzle (qkv-verified).
__global__ __launch_bounds__(512) void proj_k(const u16* __restrict__ ya, const u16* __restrict__ Wpb,
                                              const float* __restrict__ bias, float* __restrict__ out) {
    __shared__ u16 As[2][4096];               // [buf][64][64] linear (content swizzled)
    __shared__ u16 Bs[2][4096];
    int tid = threadIdx.x;
    int n0 = blockIdx.x * 64, m0 = blockIdx.y * 64;
    int w = tid >> 6, lane = tid & 63, lr = lane & 15, quad = lane >> 4;
    int wr = w >> 1, wc = w & 1;              // 4x2 wave grid
    f32x4 acc[2] = {};
    int srow = tid >> 3;                                  // staging row 0..63
    int swc8 = (((tid & 7) ^ (srow & 7)) << 3);           // pre-swizzled src col (u16)
    int soff = tid * 8;                                   // linear LDS u16 offset
    int lrx = lr & 7;                                     // fragment-read XOR key

#define PRJ_STAGE(bufi, kc) do {                                              \
        gload16(ya  + (size_t)(m0 + srow) * C_EMB + (kc) + swc8, &As[bufi][soff]); \
        gload16(Wpb + (size_t)(n0 + srow) * C_EMB + (kc) + swc8, &Bs[bufi][soff]); \
    } while (0)

    PRJ_STAGE(0, 0);
#pragma unroll 2
    for (int kt = 0; kt < 16; ++kt) {
        int cur = kt & 1;
        if (kt < 15) {
            PRJ_STAGE(cur ^ 1, (kt + 1) * 64);
            asm volatile("s_waitcnt vmcnt(2)" ::: "memory");
        } else {
            asm volatile("s_waitcnt vmcnt(0)" ::: "memory");
        }
        __builtin_amdgcn_s_barrier();
        asm volatile("" ::: "memory");
#pragma unroll
        for (int ks = 0; ks < 64; ks += 32) {
            int slot = (ks >> 3) + quad;                   // 0..7
            int rc8 = ((slot ^ lrx) << 3);                 // swizzled read col (u16)
            s16x8 af, bf[2];
            af = *(const s16x8*)&As[cur][(wr * 16 + lr) * 64 + rc8];
#pragma unroll
            for (int j = 0; j < 2; ++j)
                bf[j] = *(const s16x8*)&Bs[cur][(wc * 32 + j * 16 + lr) * 64 + rc8];
#pragma unroll
            for (int j = 0; j < 2; ++j) acc[j] = MFMA16(af, bf[j], acc[j]);
        }
        asm volatile("" ::: "memory");
        __builtin_amdgcn_s_barrier();
    }
#undef PRJ_STAGE

    float bv[2];
#pragma unroll
    for (int j = 0; j < 2; ++j) bv[j] = bias[n0 + wc * 32 + j * 16 + lr];
#pragma unroll
    for (int r = 0; r < 4; ++r) {
        int m = m0 + wr * 16 + quad * 4 + r;
#pragma unroll
        for (int j = 0; j < 2; ++j)
            out[(size_t)m * C_EMB + n0 + wc * 32 + j * 16 + lr] = acc[j][r] + bv[j];
    }
}

extern "C" void kernel_launch(void* const* d_in, const int* in_sizes, int n_in,
                              void* d_out, int out_size, void* d_ws, size_t ws_size,
                              hipStream_t stream) {
    // Inputs resolved BY ELEMENT COUNT (unique): x 4194304, W_attn 3145728,
    // b_attn 3072, W_proj 1048576, b_proj 1024. All fp32.
    const float *x = nullptr, *Wa = nullptr, *ba = nullptr, *Wp = nullptr, *bp = nullptr;
    for (int i = 0; i < n_in; ++i) {
        switch (in_sizes[i]) {
            case 4194304: x  = (const float*)d_in[i]; break;
            case 3145728: Wa = (const float*)d_in[i]; break;
            case 3072:    ba = (const float*)d_in[i]; break;
            case 1048576: Wp = (const float*)d_in[i]; break;
            case 1024:    bp = (const float*)d_in[i]; break;
            default: break;
        }
    }
    float* out = (float*)d_out;

    char* ws = (char*)d_ws;
    u16* qb     = (u16*)(ws);                    //  0.. 8 MiB  bf16 [B,H,T,D] (q*0.125*log2e)
    u16* kb     = (u16*)(ws + 8388608);          //  8..16 MiB  bf16 [B,H,T,D]
    u16* vt     = (u16*)(ws + 16777216);         // 16..24 MiB  bf16 [B,H,D,T]
    u16* yab    = (u16*)(ws + 25165824);         // 24..32 MiB  bf16 [B,T,C]
    float2* tab = (float2*)(ws + 33554432);      // 32..32.5 MiB
    u16* xb     = (u16*)(ws + 35651584);         // 34..42 MiB  bf16 [4096,1024]
    u16* Wab    = (u16*)(ws + 44040192);         // 42..48 MiB  bf16 [3072,1024]
    u16* Wpb    = (u16*)(ws + 50331648);         // 48..50 MiB  bf16 [1024,1024]

    prep_k<<<4352, 256, 0, stream>>>(x, Wa, Wp, xb, Wab, Wpb, tab);
    qkv_rope_k<<<dim3(24, 32), 512, 0, stream>>>(xb, Wab, ba, tab, qb, kb, vt);
    flash_k<<<dim3(32, 32), 256, 0, stream>>>(qb, kb, vt, yab);
    proj_k<<<dim3(16, 64), 512, 0, stream>>>(yab, Wpb, bp, out);
}